// Round 1
// baseline (504.648 us; speedup 1.0000x reference)
//
#include <hip/hip_runtime.h>

typedef unsigned short US;
typedef __attribute__((ext_vector_type(8))) short bf16x8;
typedef __attribute__((ext_vector_type(4))) float f32x4;

typedef __attribute__((address_space(1))) unsigned int uglobal;
typedef __attribute__((address_space(3))) unsigned int ulocal;

__device__ __forceinline__ void async16(const void* g, void* l) {
  __builtin_amdgcn_global_load_lds((const uglobal*)g, (ulocal*)l, 16, 0, 0);
}

// fp32 -> bf16 bits; exact for integers |v| <= 256 (low 16 mantissa bits are zero)
__device__ __forceinline__ US f2bf(float f) {
  union { float f; unsigned u; } v; v.f = f;
  return (US)(v.u >> 16);
}

// ---------------- reductions for quant scales ----------------
__global__ __launch_bounds__(256) void absmax_kernel(const float* __restrict__ in, int n4,
                                                     unsigned* __restrict__ dst) {
  float m = 0.f;
  int stride = gridDim.x * blockDim.x;
  for (int i = blockIdx.x * blockDim.x + threadIdx.x; i < n4; i += stride) {
    float4 v = ((const float4*)in)[i];
    m = fmaxf(fmaxf(fabsf(v.x), fabsf(v.y)), fmaxf(fmaxf(fabsf(v.z), fabsf(v.w)), m));
  }
  for (int off = 32; off; off >>= 1) m = fmaxf(m, __shfl_down(m, off, 64));
  __shared__ float sm[4];
  int lane = threadIdx.x & 63, wv = threadIdx.x >> 6;
  if (!lane) sm[wv] = m;
  __syncthreads();
  if (threadIdx.x == 0)
    atomicMax(dst, __float_as_uint(fmaxf(fmaxf(sm[0], sm[1]), fmaxf(sm[2], sm[3]))));
}

__global__ void prep_kernel(const unsigned* __restrict__ sc, float* __restrict__ pr) {
  float sx  = __uint_as_float(sc[0]) / 127.f + 1e-12f;
  float sw1 = __uint_as_float(sc[1]) / 127.f + 1e-12f;
  float sw2 = __uint_as_float(sc[2]) / 127.f + 1e-12f;
  pr[0] = sx; pr[1] = sw1; pr[2] = sw2; pr[3] = sx * sw1;
}

// ---------------- weight quant + relayout: w[O][C][3][3] -> wq[O][khw*256+c] ----------------
__global__ __launch_bounds__(256) void quantw_kernel(const float* __restrict__ w, US* __restrict__ wq,
                                                     const float* __restrict__ pr, int sidx) {
  int j = blockIdx.x * 256 + threadIdx.x;
  if (j >= 256 * 2304) return;
  float s = pr[sidx];
  int o = j / 2304, k = j - o * 2304, khw = k >> 8, c = k & 255;
  float q = fminf(fmaxf(rintf(w[(size_t)(o * 256 + c) * 9 + khw] / s), -128.f), 127.f);
  wq[j] = f2bf(q);
}

// ---------------- x quant + NCHW -> halo'd NHWC bf16  ----------------
// block = (n,h); halo layout [64][34][34][256], borders pre-zeroed by memset
__global__ __launch_bounds__(256) void quantx_kernel(const float* __restrict__ x,
                                                     US* __restrict__ halo,
                                                     const float* __restrict__ pr) {
  int n = blockIdx.x >> 5, h = blockIdx.x & 31;
  float s = pr[0];
  __shared__ float lds[32 * 257];
  const float* src = x + (size_t)n * 256 * 1024 + h * 32;
  int t = threadIdx.x;
  int wloc = t & 31, crow = t >> 5;
  for (int cc = 0; cc < 256; cc += 8) {
    int c = cc + crow;
    lds[wloc * 257 + c] = src[(size_t)c * 1024 + wloc];
  }
  __syncthreads();
  US* dst = halo + ((size_t)((n * 34 + h + 1) * 34) + 1) * 256;
  for (int w_ = 0; w_ < 32; ++w_) {
    float v = lds[w_ * 257 + t];
    float q = fminf(fmaxf(rintf(v / s), -128.f), 127.f);
    dst[(size_t)w_ * 256 + t] = f2bf(q);
  }
}

// ---------------- implicit-GEMM conv, 128x128 tile, BK=32, double-buffered LDS ----------------
// MODE 0: M-side = activation pixels, N-side = weights, out[pixel*256 + o]   (conv1)
// MODE 1: M-side = weights (o),      N-side = act pixels, out[o*65536 + p]   (conv2, NCHW out)
template <int MODE>
__global__ __launch_bounds__(256) void conv_gemm_kernel(const US* __restrict__ acth,
                                                        const US* __restrict__ wq,
                                                        float* __restrict__ out,
                                                        const float* __restrict__ pr) {
  __shared__ __align__(16) US Alds[2][4096];
  __shared__ __align__(16) US Blds[2][4096];
  const int tid = threadIdx.x, lane = tid & 63, wid = tid >> 6;
  const int bid = blockIdx.x;
  const int mb = (MODE == 0) ? (bid >> 1) : (bid & 1);
  const int nb = (MODE == 0) ? (bid & 1) : (bid >> 1);
  const int actBase = ((MODE == 0) ? mb : nb) * 128;
  const int wBase   = ((MODE == 0) ? nb : mb) * 128;

  long aoff[2], woff[2];
  for (int r = 0; r < 2; ++r) {
    int row = r * 64 + wid * 16 + (lane >> 2);
    int p = actBase + row;
    int n = p >> 10, h = (p >> 5) & 31, w_ = p & 31;
    aoff[r] = (long)((n * 34 + h) * 34 + w_) * 512 + (lane & 3) * 16;
    woff[r] = (long)(wBase + row) * 4608 + (lane & 3) * 16;
  }
  const char* actc = (const char*)acth;
  const char* wqc  = (const char*)wq;
  char* ldsA = (char*)&Alds[0][0];
  char* ldsB = (char*)&Blds[0][0];
  char* ldsAct = (MODE == 0) ? ldsA : ldsB;
  char* ldsW   = (MODE == 0) ? ldsB : ldsA;

  f32x4 acc[4][4];
#pragma unroll
  for (int m = 0; m < 4; ++m)
#pragma unroll
    for (int n = 0; n < 4; ++n)
#pragma unroll
      for (int r = 0; r < 4; ++r) acc[m][n][r] = 0.f;

  const int wm = wid >> 1, wn = wid & 1;

  auto stage = [&](int buf, int kc) {
    int khw = kc >> 3;
    int kh = khw / 3, kw = khw - kh * 3;
    long uA = (long)(kh * 34 + kw) * 512 + (kc & 7) * 64;
    long uW = (long)kc * 64;
#pragma unroll
    for (int r = 0; r < 2; ++r) {
      int ldsOff = buf * 8192 + r * 4096 + wid * 1024;
      async16(actc + aoff[r] + uA, ldsAct + ldsOff);
      async16(wqc + woff[r] + uW, ldsW + ldsOff);
    }
  };

  stage(0, 0);
  __syncthreads();

  for (int kc = 0; kc < 72; ++kc) {
    int cur = kc & 1;
    if (kc + 1 < 72) stage(cur ^ 1, kc + 1);
    const US* As = &Alds[cur][0];
    const US* Bs = &Blds[cur][0];
    int ro = (lane & 15) * 32 + (lane >> 4) * 8;
    bf16x8 a[4], b[4];
#pragma unroll
    for (int m = 0; m < 4; ++m) a[m] = *(const bf16x8*)(As + (wm * 64 + m * 16) * 32 + ro);
#pragma unroll
    for (int n = 0; n < 4; ++n) b[n] = *(const bf16x8*)(Bs + (wn * 64 + n * 16) * 32 + ro);
#pragma unroll
    for (int m = 0; m < 4; ++m)
#pragma unroll
      for (int n = 0; n < 4; ++n)
        acc[m][n] = __builtin_amdgcn_mfma_f32_16x16x32_bf16(a[m], b[n], acc[m][n], 0, 0, 0);
    __syncthreads();
  }

  const float s = pr[MODE ? 5 : 3];
  const int ldC = MODE ? 65536 : 256;
  const int rowBase = mb * 128 + wm * 64;
  const int colBase = nb * 128 + wn * 64 + (lane & 15);
#pragma unroll
  for (int m = 0; m < 4; ++m) {
    int row0 = rowBase + m * 16 + (lane >> 4) * 4;
#pragma unroll
    for (int n = 0; n < 4; ++n) {
      int col = colBase + n * 16;
#pragma unroll
      for (int r = 0; r < 4; ++r)
        out[(size_t)(row0 + r) * ldC + col] = acc[m][n][r] * s;
    }
  }
}

// ---------------- BN1 stats (two-stage) ----------------
__global__ __launch_bounds__(256) void stats1_kernel(const float* __restrict__ y,
                                                     float* __restrict__ part) {
  int o = threadIdx.x, pb = blockIdx.x;
  const float* p0 = y + (size_t)pb * 65536 + o;
  float s = 0.f, ss = 0.f, mx = -3.4e38f, mn = 3.4e38f;
  for (int p = 0; p < 256; ++p) {
    float v = p0[(size_t)p * 256];
    s += v; ss += v * v; mx = fmaxf(mx, v); mn = fminf(mn, v);
  }
  int i = pb * 256 + o;
  part[i] = s; part[65536 + i] = ss; part[131072 + i] = mx; part[196608 + i] = mn;
}

__global__ __launch_bounds__(256) void finalize1_kernel(const float* __restrict__ part,
                                                        const float* __restrict__ g,
                                                        const float* __restrict__ be,
                                                        float* __restrict__ bnA, float* __restrict__ bnB,
                                                        float* __restrict__ pr) {
  int o = threadIdx.x;
  float s = 0.f, ss = 0.f, mx = -3.4e38f, mn = 3.4e38f;
  for (int b = 0; b < 256; ++b) {
    int i = b * 256 + o;
    s += part[i]; ss += part[65536 + i];
    mx = fmaxf(mx, part[131072 + i]); mn = fminf(mn, part[196608 + i]);
  }
  float mean = s * (1.f / 65536.f);
  float var = fmaxf(ss * (1.f / 65536.f) - mean * mean, 0.f);
  float a = g[o] * rsqrtf(var + 1e-5f);
  float b2 = be[o] - mean * a;
  bnA[o] = a; bnB[o] = b2;
  // global max of relu(BN(y)) via per-channel extremes (BN is monotone affine)
  __shared__ float red[256];
  red[o] = fmaxf(a * mx + b2, a * mn + b2);
  __syncthreads();
  for (int st = 128; st; st >>= 1) {
    if (o < st) red[o] = fmaxf(red[o], red[o + st]);
    __syncthreads();
  }
  if (o == 0) {
    float s2 = fmaxf(red[0], 0.f) / 255.f + 1e-12f;
    pr[4] = s2; pr[5] = s2 * pr[2];
  }
}

// ---------------- BN1 apply + ReLU + unsigned quant -> halo (reused) ----------------
__global__ __launch_bounds__(256) void apply_kernel(const float* __restrict__ y,
                                                    const float* __restrict__ bnA,
                                                    const float* __restrict__ bnB,
                                                    const float* __restrict__ pr,
                                                    US* __restrict__ halo) {
  int o = threadIdx.x;
  float a = bnA[o], b = bnB[o], s2 = pr[4];
  int p0 = blockIdx.x * 16;
  for (int j = 0; j < 16; ++j) {
    int p = p0 + j;
    float v = fmaxf(a * y[(size_t)p * 256 + o] + b, 0.f);
    float q = fminf(fmaxf(rintf(v / s2), 0.f), 255.f);
    int n = p >> 10, h = (p >> 5) & 31, w_ = p & 31;
    halo[((size_t)((n * 34 + h + 1) * 34) + (w_ + 1)) * 256 + o] = f2bf(q);
  }
}

// ---------------- BN2 stats: one block per channel (conv2 out is [o][p]) ----------------
__global__ __launch_bounds__(256) void stats2_kernel(const float* __restrict__ y2,
                                                     const float* __restrict__ g,
                                                     const float* __restrict__ be,
                                                     float* __restrict__ bnA2, float* __restrict__ bnB2) {
  int o = blockIdx.x;
  const float4* row = (const float4*)(y2 + (size_t)o * 65536);
  float s = 0.f, ss = 0.f;
  for (int i = threadIdx.x; i < 16384; i += 256) {
    float4 v = row[i];
    s += v.x + v.y + v.z + v.w;
    ss += v.x * v.x + v.y * v.y + v.z * v.z + v.w * v.w;
  }
  for (int off = 32; off; off >>= 1) { s += __shfl_down(s, off, 64); ss += __shfl_down(ss, off, 64); }
  __shared__ float as_[4], bs_[4];
  int lane = threadIdx.x & 63, wv = threadIdx.x >> 6;
  if (!lane) { as_[wv] = s; bs_[wv] = ss; }
  __syncthreads();
  if (threadIdx.x == 0) {
    s = as_[0] + as_[1] + as_[2] + as_[3];
    ss = bs_[0] + bs_[1] + bs_[2] + bs_[3];
    float mean = s * (1.f / 65536.f);
    float var = fmaxf(ss * (1.f / 65536.f) - mean * mean, 0.f);
    float a = g[o] * rsqrtf(var + 1e-5f);
    bnA2[o] = a;
    bnB2[o] = be[o] - mean * a;
  }
}

// ---------------- BN2 + residual + ReLU -> NCHW out ----------------
__global__ __launch_bounds__(256) void final_kernel(const float* __restrict__ y2,
                                                    const float* __restrict__ x,
                                                    const float* __restrict__ bnA2,
                                                    const float* __restrict__ bnB2,
                                                    float* __restrict__ out) {
  int tid = blockIdx.x * 256 + threadIdx.x;
  for (int i = tid; i < 4194304; i += 1048576) {
    int e = i << 2;
    int o = (e >> 10) & 255;
    int n = e >> 18, hw = e & 1023;
    float4 v = *(const float4*)(y2 + (((size_t)o << 16) + (n << 10) + hw));
    float4 xr = ((const float4*)x)[i];
    float a = bnA2[o], b = bnB2[o];
    float4 r;
    r.x = fmaxf(a * v.x + b + xr.x, 0.f);
    r.y = fmaxf(a * v.y + b + xr.y, 0.f);
    r.z = fmaxf(a * v.z + b + xr.z, 0.f);
    r.w = fmaxf(a * v.w + b + xr.w, 0.f);
    ((float4*)out)[i] = r;
  }
}

extern "C" void kernel_launch(void* const* d_in, const int* in_sizes, int n_in,
                              void* d_out, int out_size, void* d_ws, size_t ws_size,
                              hipStream_t stream) {
  const float* x  = (const float*)d_in[0];
  const float* w1 = (const float*)d_in[1];
  const float* g1 = (const float*)d_in[2];
  const float* b1 = (const float*)d_in[3];
  const float* w2 = (const float*)d_in[4];
  const float* g2 = (const float*)d_in[5];
  const float* b2 = (const float*)d_in[6];
  float* out = (float*)d_out;
  char* ws = (char*)d_ws;

  // workspace layout (total ~103.4 MB)
  unsigned* sc = (unsigned*)ws;                       // 4 KB, zeroed
  float* pr    = (float*)(ws + 4096);                 // scales
  float* bnA   = (float*)(ws + 8192);
  float* bnB   = (float*)(ws + 12288);
  float* bnA2  = (float*)(ws + 16384);
  float* bnB2  = (float*)(ws + 20480);
  float* part  = (float*)(ws + 24576);                // 1 MB
  US* wq1  = (US*)(ws + 24576 + 1048576);             // 1.125 MB
  US* wq2  = (US*)(ws + 24576 + 1048576 + 1179648);   // 1.125 MB
  US* halo = (US*)(ws + 24576 + 1048576 + 2 * 1179648);           // 36.1 MB, zeroed
  float* convb = (float*)(ws + 24576 + 1048576 + 2 * 1179648 + 37879808); // 64 MB

  hipMemsetAsync(sc, 0, 4096, stream);
  hipMemsetAsync(halo, 0, 37879808, stream);

  absmax_kernel<<<2048, 256, 0, stream>>>(x, 16777216 / 4, sc + 0);
  absmax_kernel<<<256, 256, 0, stream>>>(w1, 589824 / 4, sc + 1);
  absmax_kernel<<<256, 256, 0, stream>>>(w2, 589824 / 4, sc + 2);
  prep_kernel<<<1, 1, 0, stream>>>(sc, pr);
  quantw_kernel<<<2304, 256, 0, stream>>>(w1, wq1, pr, 1);
  quantw_kernel<<<2304, 256, 0, stream>>>(w2, wq2, pr, 2);
  quantx_kernel<<<2048, 256, 0, stream>>>(x, halo, pr);
  conv_gemm_kernel<0><<<1024, 256, 0, stream>>>(halo, wq1, convb, pr);
  stats1_kernel<<<256, 256, 0, stream>>>(convb, part);
  finalize1_kernel<<<1, 256, 0, stream>>>(part, g1, b1, bnA, bnB, pr);
  apply_kernel<<<4096, 256, 0, stream>>>(convb, bnA, bnB, pr, halo);
  conv_gemm_kernel<1><<<1024, 256, 0, stream>>>(halo, wq2, convb, pr);
  stats2_kernel<<<256, 256, 0, stream>>>(convb, g2, b2, bnA2, bnB2);
  final_kernel<<<4096, 256, 0, stream>>>(convb, x, bnA2, bnB2, out);
}

// Round 2
// 489.628 us; speedup vs baseline: 1.0307x; 1.0307x over previous
//
#include <hip/hip_runtime.h>

typedef unsigned short US;
typedef __attribute__((ext_vector_type(8))) short bf16x8;
typedef __attribute__((ext_vector_type(4))) float f32x4;

typedef __attribute__((address_space(1))) unsigned int uglobal;
typedef __attribute__((address_space(3))) unsigned int ulocal;

__device__ __forceinline__ void async16(const void* g, void* l) {
  __builtin_amdgcn_global_load_lds((const uglobal*)g, (ulocal*)l, 16, 0, 0);
}

// fp32 -> bf16 bits; exact for integers |v| <= 256
__device__ __forceinline__ US f2bf(float f) {
  union { float f; unsigned u; } v; v.f = f;
  return (US)(v.u >> 16);
}

// ---------------- reductions for quant scales ----------------
__global__ __launch_bounds__(256) void absmax_kernel(const float* __restrict__ in, int n4,
                                                     unsigned* __restrict__ dst) {
  float m = 0.f;
  int stride = gridDim.x * blockDim.x;
  for (int i = blockIdx.x * blockDim.x + threadIdx.x; i < n4; i += stride) {
    float4 v = ((const float4*)in)[i];
    m = fmaxf(fmaxf(fabsf(v.x), fabsf(v.y)), fmaxf(fmaxf(fabsf(v.z), fabsf(v.w)), m));
  }
  for (int off = 32; off; off >>= 1) m = fmaxf(m, __shfl_down(m, off, 64));
  __shared__ float sm[4];
  int lane = threadIdx.x & 63, wv = threadIdx.x >> 6;
  if (!lane) sm[wv] = m;
  __syncthreads();
  if (threadIdx.x == 0)
    atomicMax(dst, __float_as_uint(fmaxf(fmaxf(sm[0], sm[1]), fmaxf(sm[2], sm[3]))));
}

__global__ void prep_kernel(const unsigned* __restrict__ sc, float* __restrict__ pr) {
  float sx  = __uint_as_float(sc[0]) / 127.f + 1e-12f;
  float sw1 = __uint_as_float(sc[1]) / 127.f + 1e-12f;
  float sw2 = __uint_as_float(sc[2]) / 127.f + 1e-12f;
  pr[0] = sx; pr[1] = sw1; pr[2] = sw2; pr[3] = sx * sw1;
}

// ---------------- weight quant + relayout: w[O][C][3][3] -> wq[O][khw*256+c] ----------------
__global__ __launch_bounds__(256) void quantw_kernel(const float* __restrict__ w, US* __restrict__ wq,
                                                     const float* __restrict__ pr, int sidx) {
  int j = blockIdx.x * 256 + threadIdx.x;
  if (j >= 256 * 2304) return;
  float s = pr[sidx];
  int o = j / 2304, k = j - o * 2304, khw = k >> 8, c = k & 255;
  float q = fminf(fmaxf(rintf(w[(size_t)(o * 256 + c) * 9 + khw] / s), -128.f), 127.f);
  wq[j] = f2bf(q);
}

// ---------------- x quant + NCHW -> halo'd NHWC bf16 ----------------
__global__ __launch_bounds__(256) void quantx_kernel(const float* __restrict__ x,
                                                     US* __restrict__ halo,
                                                     const float* __restrict__ pr) {
  int n = blockIdx.x >> 5, h = blockIdx.x & 31;
  float s = pr[0];
  __shared__ float lds[32 * 257];
  const float* src = x + (size_t)n * 256 * 1024 + h * 32;
  int t = threadIdx.x;
  int wloc = t & 31, crow = t >> 5;
  for (int cc = 0; cc < 256; cc += 8) {
    int c = cc + crow;
    lds[wloc * 257 + c] = src[(size_t)c * 1024 + wloc];
  }
  __syncthreads();
  US* dst = halo + ((size_t)((n * 34 + h + 1) * 34) + 1) * 256;
  for (int w_ = 0; w_ < 32; ++w_) {
    float v = lds[w_ * 257 + t];
    float q = fminf(fmaxf(rintf(v / s), -128.f), 127.f);
    dst[(size_t)w_ * 256 + t] = f2bf(q);
  }
}

// ---------------- implicit-GEMM conv, 128x128 tile, BK=32, double-buffered LDS ----------------
// k-order: c-outer, khw-inner (L2-friendly: halo re-reads 1 k-step apart)
// MODE 0: M = act pixels, N = out channels, out[p*256+o]; partial BN1 stats (sum/ss/min/max)
// MODE 1: M = out channels, N = act pixels, out[o*65536+p]; partial BN2 stats (sum/ss)
template <int MODE>
__global__ __launch_bounds__(256) void conv_gemm_kernel(const US* __restrict__ acth,
                                                        const US* __restrict__ wq,
                                                        float* __restrict__ out,
                                                        const float* __restrict__ pr,
                                                        const unsigned* __restrict__ sc,
                                                        float* __restrict__ part) {
  __shared__ __align__(16) US Alds[2][4096];
  __shared__ __align__(16) US Blds[2][4096];
  const int tid = threadIdx.x, lane = tid & 63, wid = tid >> 6;
  int bid = blockIdx.x;
  bid = (bid & 7) * 128 + (bid >> 3);  // T1 XCD-chunked swizzle (1024 % 8 == 0)
  const int mb = (MODE == 0) ? (bid >> 1) : (bid & 1);
  const int nb = (MODE == 0) ? (bid & 1) : (bid >> 1);
  const int actBase = ((MODE == 0) ? mb : nb) * 128;
  const int wBase   = ((MODE == 0) ? nb : mb) * 128;

  long aoff[2], woff[2];
  for (int r = 0; r < 2; ++r) {
    int row = r * 64 + wid * 16 + (lane >> 2);
    int p = actBase + row;
    int n = p >> 10, h = (p >> 5) & 31, w_ = p & 31;
    aoff[r] = (long)((n * 34 + h) * 34 + w_) * 512 + (lane & 3) * 16;
    woff[r] = (long)(wBase + row) * 4608 + (lane & 3) * 16;
  }
  const char* actc = (const char*)acth;
  const char* wqc  = (const char*)wq;
  char* ldsA = (char*)&Alds[0][0];
  char* ldsB = (char*)&Blds[0][0];
  char* ldsAct = (MODE == 0) ? ldsA : ldsB;
  char* ldsW   = (MODE == 0) ? ldsB : ldsA;

  f32x4 acc[4][4];
#pragma unroll
  for (int m = 0; m < 4; ++m)
#pragma unroll
    for (int n = 0; n < 4; ++n)
#pragma unroll
      for (int r = 0; r < 4; ++r) acc[m][n][r] = 0.f;

  const int wm = wid >> 1, wn = wid & 1;

  auto stage = [&](int buf, int kc) {
    int cchunk = kc / 9;         // 32-channel chunk (outer)
    int khw = kc - cchunk * 9;   // filter tap (inner)
    int kh = khw / 3, kw = khw - kh * 3;
    long uA = (long)(kh * 34 + kw) * 512 + cchunk * 64;
    long uW = (long)khw * 512 + cchunk * 64;
#pragma unroll
    for (int r = 0; r < 2; ++r) {
      int ldsOff = buf * 8192 + r * 4096 + wid * 1024;
      async16(actc + aoff[r] + uA, ldsAct + ldsOff);
      async16(wqc + woff[r] + uW, ldsW + ldsOff);
    }
  };

  stage(0, 0);
  __syncthreads();

  for (int kc = 0; kc < 72; ++kc) {
    int cur = kc & 1;
    if (kc + 1 < 72) stage(cur ^ 1, kc + 1);
    const US* As = &Alds[cur][0];
    const US* Bs = &Blds[cur][0];
    int ro = (lane & 15) * 32 + (lane >> 4) * 8;
    bf16x8 a[4], b[4];
#pragma unroll
    for (int m = 0; m < 4; ++m) a[m] = *(const bf16x8*)(As + (wm * 64 + m * 16) * 32 + ro);
#pragma unroll
    for (int n = 0; n < 4; ++n) b[n] = *(const bf16x8*)(Bs + (wn * 64 + n * 16) * 32 + ro);
#pragma unroll
    for (int m = 0; m < 4; ++m)
#pragma unroll
      for (int n = 0; n < 4; ++n)
        acc[m][n] = __builtin_amdgcn_mfma_f32_16x16x32_bf16(a[m], b[n], acc[m][n], 0, 0, 0);
    __syncthreads();
  }

  const float s = (MODE == 0) ? pr[3]
                              : ((__uint_as_float(sc[3]) / 255.f + 1e-12f) * pr[2]);
  const int ldC = MODE ? 65536 : 256;
  const int rowBase = mb * 128 + wm * 64;
  const int colBase = nb * 128 + wn * 64 + (lane & 15);

  if constexpr (MODE == 0) {
    // write + per-channel partial {sum, sumsq, max, min} over this block's 128 pixels
    float vs[4], vss[4], vmx[4], vmn[4];
#pragma unroll
    for (int n = 0; n < 4; ++n) { vs[n] = 0.f; vss[n] = 0.f; vmx[n] = -3.4e38f; vmn[n] = 3.4e38f; }
#pragma unroll
    for (int m = 0; m < 4; ++m) {
      int row0 = rowBase + m * 16 + (lane >> 4) * 4;
#pragma unroll
      for (int n = 0; n < 4; ++n) {
        int col = colBase + n * 16;
#pragma unroll
        for (int r = 0; r < 4; ++r) {
          float v = acc[m][n][r] * s;
          out[(size_t)(row0 + r) * ldC + col] = v;
          vs[n] += v; vss[n] += v * v;
          vmx[n] = fmaxf(vmx[n], v); vmn[n] = fminf(vmn[n], v);
        }
      }
    }
    // reduce across the 4 row-groups (lane>>4); channel depends only on lane&15
#pragma unroll
    for (int off = 16; off <= 32; off <<= 1)
#pragma unroll
      for (int n = 0; n < 4; ++n) {
        vs[n] += __shfl_xor(vs[n], off, 64);
        vss[n] += __shfl_xor(vss[n], off, 64);
        vmx[n] = fmaxf(vmx[n], __shfl_xor(vmx[n], off, 64));
        vmn[n] = fminf(vmn[n], __shfl_xor(vmn[n], off, 64));
      }
    float* sred = (float*)&Alds[0][0];   // [2 wm][128 ch]
    float* ssred = sred + 256;
    float* mxred = sred + 512;
    float* mnred = sred + 768;
    if (lane < 16) {
#pragma unroll
      for (int n = 0; n < 4; ++n) {
        int c = wn * 64 + n * 16 + lane;
        sred[wm * 128 + c] = vs[n]; ssred[wm * 128 + c] = vss[n];
        mxred[wm * 128 + c] = vmx[n]; mnred[wm * 128 + c] = vmn[n];
      }
    }
    __syncthreads();
    if (tid < 128) {
      int idx = mb * 256 + nb * 128 + tid;   // [512 mb][256 ch]
      part[idx]          = sred[tid] + sred[128 + tid];
      part[131072 + idx] = ssred[tid] + ssred[128 + tid];
      part[262144 + idx] = fmaxf(mxred[tid], mxred[128 + tid]);
      part[393216 + idx] = fminf(mnred[tid], mnred[128 + tid]);
    }
  } else {
    // write + per-o-channel partial {sum, sumsq} over this block's 128 pixels
    float rs_[4][4], rss_[4][4];
#pragma unroll
    for (int m = 0; m < 4; ++m)
#pragma unroll
      for (int r = 0; r < 4; ++r) { rs_[m][r] = 0.f; rss_[m][r] = 0.f; }
#pragma unroll
    for (int m = 0; m < 4; ++m) {
      int row0 = rowBase + m * 16 + (lane >> 4) * 4;
#pragma unroll
      for (int n = 0; n < 4; ++n) {
        int col = colBase + n * 16;
#pragma unroll
        for (int r = 0; r < 4; ++r) {
          float v = acc[m][n][r] * s;
          out[(size_t)(row0 + r) * ldC + col] = v;
          rs_[m][r] += v; rss_[m][r] += v * v;
        }
      }
    }
    // reduce over the 16 lanes of each row-group (cols); row depends on lane>>4 only
#pragma unroll
    for (int off = 1; off <= 8; off <<= 1)
#pragma unroll
      for (int m = 0; m < 4; ++m)
#pragma unroll
        for (int r = 0; r < 4; ++r) {
          rs_[m][r] += __shfl_xor(rs_[m][r], off, 64);
          rss_[m][r] += __shfl_xor(rss_[m][r], off, 64);
        }
    float* rsum = (float*)&Alds[0][0];   // [2 wn][128 row]
    float* rss = rsum + 256;
    if ((lane & 15) == 0) {
      int g = lane >> 4;
#pragma unroll
      for (int m = 0; m < 4; ++m)
#pragma unroll
        for (int r = 0; r < 4; ++r) {
          int row = wm * 64 + m * 16 + g * 4 + r;
          rsum[wn * 128 + row] = rs_[m][r];
          rss[wn * 128 + row] = rss_[m][r];
        }
    }
    __syncthreads();
    if (tid < 128) {
      int idx = nb * 256 + mb * 128 + tid;   // [512 nb][256 o]
      part[idx]          = rsum[tid] + rsum[128 + tid];
      part[131072 + idx] = rss[tid] + rss[128 + tid];
    }
  }
}

// ---------------- BN1 finalize: reduce 512 partials/ch -> bnA,bnB + relu-max -> sc[3] ----------------
__global__ __launch_bounds__(256) void bn1fin_kernel(const float* __restrict__ part,
                                                     const float* __restrict__ g,
                                                     const float* __restrict__ be,
                                                     float* __restrict__ bnA, float* __restrict__ bnB,
                                                     unsigned* __restrict__ sc) {
  int o0 = blockIdx.x * 32;
  int t = threadIdx.x, oc = t & 31, mq = t >> 5;  // 8 groups x 64 rows
  float s = 0.f, ss = 0.f, mx = -3.4e38f, mn = 3.4e38f;
  for (int j = 0; j < 64; ++j) {
    int i = (mq * 64 + j) * 256 + o0 + oc;
    s += part[i]; ss += part[131072 + i];
    mx = fmaxf(mx, part[262144 + i]); mn = fminf(mn, part[393216 + i]);
  }
  __shared__ float red[4][8][32];
  red[0][mq][oc] = s; red[1][mq][oc] = ss; red[2][mq][oc] = mx; red[3][mq][oc] = mn;
  __syncthreads();
  if (t < 32) {
    s = 0.f; ss = 0.f; mx = -3.4e38f; mn = 3.4e38f;
    for (int q = 0; q < 8; ++q) {
      s += red[0][q][t]; ss += red[1][q][t];
      mx = fmaxf(mx, red[2][q][t]); mn = fminf(mn, red[3][q][t]);
    }
    float mean = s * (1.f / 65536.f);
    float var = fmaxf(ss * (1.f / 65536.f) - mean * mean, 0.f);
    int o = o0 + t;
    float a = g[o] * rsqrtf(var + 1e-5f);
    float b2 = be[o] - mean * a;
    bnA[o] = a; bnB[o] = b2;
    float m = fmaxf(fmaxf(a * mx + b2, a * mn + b2), 0.f);
    atomicMax(sc + 3, __float_as_uint(m));   // nonneg float bits are order-preserving
  }
}

// ---------------- BN2 finalize ----------------
__global__ __launch_bounds__(256) void bn2fin_kernel(const float* __restrict__ part,
                                                     const float* __restrict__ g,
                                                     const float* __restrict__ be,
                                                     float* __restrict__ bnA2, float* __restrict__ bnB2) {
  int o0 = blockIdx.x * 32;
  int t = threadIdx.x, oc = t & 31, mq = t >> 5;
  float s = 0.f, ss = 0.f;
  for (int j = 0; j < 64; ++j) {
    int i = (mq * 64 + j) * 256 + o0 + oc;
    s += part[i]; ss += part[131072 + i];
  }
  __shared__ float red[2][8][32];
  red[0][mq][oc] = s; red[1][mq][oc] = ss;
  __syncthreads();
  if (t < 32) {
    s = 0.f; ss = 0.f;
    for (int q = 0; q < 8; ++q) { s += red[0][q][t]; ss += red[1][q][t]; }
    float mean = s * (1.f / 65536.f);
    float var = fmaxf(ss * (1.f / 65536.f) - mean * mean, 0.f);
    int o = o0 + t;
    float a = g[o] * rsqrtf(var + 1e-5f);
    bnA2[o] = a;
    bnB2[o] = be[o] - mean * a;
  }
}

// ---------------- BN1 apply + ReLU + unsigned quant -> halo (vectorized) ----------------
__global__ __launch_bounds__(256) void apply_kernel(const float* __restrict__ y,
                                                    const float* __restrict__ bnA,
                                                    const float* __restrict__ bnB,
                                                    const unsigned* __restrict__ sc,
                                                    US* __restrict__ halo) {
  int t = threadIdx.x;
  int c4 = (t & 63) * 4;
  int psub = t >> 6;
  float s2 = __uint_as_float(sc[3]) / 255.f + 1e-12f;
  float4 a = *(const float4*)(bnA + c4);
  float4 b = *(const float4*)(bnB + c4);
  int p0 = blockIdx.x * 16 + psub;
  for (int j = 0; j < 4; ++j) {
    int p = p0 + j * 4;
    float4 v = *(const float4*)(y + (size_t)p * 256 + c4);
    ushort4 q;
    q.x = f2bf(fminf(fmaxf(rintf(fmaxf(a.x * v.x + b.x, 0.f) / s2), 0.f), 255.f));
    q.y = f2bf(fminf(fmaxf(rintf(fmaxf(a.y * v.y + b.y, 0.f) / s2), 0.f), 255.f));
    q.z = f2bf(fminf(fmaxf(rintf(fmaxf(a.z * v.z + b.z, 0.f) / s2), 0.f), 255.f));
    q.w = f2bf(fminf(fmaxf(rintf(fmaxf(a.w * v.w + b.w, 0.f) / s2), 0.f), 255.f));
    int n = p >> 10, h = (p >> 5) & 31, w_ = p & 31;
    *(ushort4*)(halo + ((size_t)((n * 34 + h + 1) * 34) + (w_ + 1)) * 256 + c4) = q;
  }
}

// ---------------- BN2 + residual + ReLU -> NCHW out ----------------
__global__ __launch_bounds__(256) void final_kernel(const float* __restrict__ y2,
                                                    const float* __restrict__ x,
                                                    const float* __restrict__ bnA2,
                                                    const float* __restrict__ bnB2,
                                                    float* __restrict__ out) {
  int tid = blockIdx.x * 256 + threadIdx.x;
  for (int i = tid; i < 4194304; i += 1048576) {
    int e = i << 2;
    int o = (e >> 10) & 255;
    int n = e >> 18, hw = e & 1023;
    float4 v = *(const float4*)(y2 + (((size_t)o << 16) + (n << 10) + hw));
    float4 xr = ((const float4*)x)[i];
    float a = bnA2[o], b = bnB2[o];
    float4 r;
    r.x = fmaxf(a * v.x + b + xr.x, 0.f);
    r.y = fmaxf(a * v.y + b + xr.y, 0.f);
    r.z = fmaxf(a * v.z + b + xr.z, 0.f);
    r.w = fmaxf(a * v.w + b + xr.w, 0.f);
    ((float4*)out)[i] = r;
  }
}

extern "C" void kernel_launch(void* const* d_in, const int* in_sizes, int n_in,
                              void* d_out, int out_size, void* d_ws, size_t ws_size,
                              hipStream_t stream) {
  const float* x  = (const float*)d_in[0];
  const float* w1 = (const float*)d_in[1];
  const float* g1 = (const float*)d_in[2];
  const float* b1 = (const float*)d_in[3];
  const float* w2 = (const float*)d_in[4];
  const float* g2 = (const float*)d_in[5];
  const float* b2 = (const float*)d_in[6];
  float* out = (float*)d_out;
  char* ws = (char*)d_ws;

  // workspace layout (~104.4 MB)
  unsigned* sc = (unsigned*)ws;                    // scales + chmax (sc[3]), zeroed
  float* pr    = (float*)(ws + 4096);
  float* bnA   = (float*)(ws + 8192);
  float* bnB   = (float*)(ws + 12288);
  float* bnA2  = (float*)(ws + 16384);
  float* bnB2  = (float*)(ws + 20480);
  float* part  = (float*)(ws + 24576);             // 2 MB (4 slabs conv1 / 2 slabs conv2, aliased)
  US* wq1  = (US*)(ws + 24576 + 2097152);
  US* wq2  = (US*)(ws + 24576 + 2097152 + 1179648);
  US* halo = (US*)(ws + 24576 + 2097152 + 2 * 1179648);                       // 36.1 MB, zeroed
  float* convb = (float*)(ws + 24576 + 2097152 + 2 * 1179648 + 37879808);     // 64 MB

  hipMemsetAsync(sc, 0, 4096, stream);
  hipMemsetAsync(halo, 0, 37879808, stream);

  absmax_kernel<<<2048, 256, 0, stream>>>(x, 16777216 / 4, sc + 0);
  absmax_kernel<<<256, 256, 0, stream>>>(w1, 589824 / 4, sc + 1);
  absmax_kernel<<<256, 256, 0, stream>>>(w2, 589824 / 4, sc + 2);
  prep_kernel<<<1, 1, 0, stream>>>(sc, pr);
  quantw_kernel<<<2304, 256, 0, stream>>>(w1, wq1, pr, 1);
  quantw_kernel<<<2304, 256, 0, stream>>>(w2, wq2, pr, 2);
  quantx_kernel<<<2048, 256, 0, stream>>>(x, halo, pr);
  conv_gemm_kernel<0><<<1024, 256, 0, stream>>>(halo, wq1, convb, pr, sc, part);
  bn1fin_kernel<<<8, 256, 0, stream>>>(part, g1, b1, bnA, bnB, sc);
  apply_kernel<<<4096, 256, 0, stream>>>(convb, bnA, bnB, sc, halo);
  conv_gemm_kernel<1><<<1024, 256, 0, stream>>>(halo, wq2, convb, pr, sc, part);
  bn2fin_kernel<<<8, 256, 0, stream>>>(part, g2, b2, bnA2, bnB2);
  final_kernel<<<4096, 256, 0, stream>>>(convb, x, bnA2, bnB2, out);
}

// Round 3
// 367.073 us; speedup vs baseline: 1.3748x; 1.3339x over previous
//
#include <hip/hip_runtime.h>

typedef unsigned short US;
typedef __attribute__((ext_vector_type(8))) short bf16x8;
typedef __attribute__((ext_vector_type(4))) float f32x4;

typedef __attribute__((address_space(1))) unsigned int uglobal;
typedef __attribute__((address_space(3))) unsigned int ulocal;

__device__ __forceinline__ void async16(const void* g, void* l) {
  __builtin_amdgcn_global_load_lds((const uglobal*)g, (ulocal*)l, 16, 0, 0);
}

// fp32 -> bf16 bits; exact for integers |v| <= 256
__device__ __forceinline__ US f2bf(float f) {
  union { float f; unsigned u; } v; v.f = f;
  return (US)(v.u >> 16);
}

__device__ __forceinline__ float u2f(unsigned u) { return __uint_as_float(u); }

// ---------------- fused absmax over x, w1, w2 ----------------
__global__ __launch_bounds__(256) void absmax3_kernel(const float* __restrict__ x,
                                                      const float* __restrict__ w1,
                                                      const float* __restrict__ w2,
                                                      unsigned* __restrict__ sc) {
  int b = blockIdx.x;
  const float* src; int n4, b0, nb, seg;
  if (b < 1792)      { src = x;  n4 = 4194304; b0 = 0;    nb = 1792; seg = 0; }
  else if (b < 1856) { src = w1; n4 = 147456;  b0 = 1792; nb = 64;   seg = 1; }
  else               { src = w2; n4 = 147456;  b0 = 1856; nb = 64;   seg = 2; }
  float m = 0.f;
  int stride = nb * 256;
  for (int i = (b - b0) * 256 + threadIdx.x; i < n4; i += stride) {
    float4 v = ((const float4*)src)[i];
    m = fmaxf(fmaxf(fabsf(v.x), fabsf(v.y)), fmaxf(fmaxf(fabsf(v.z), fabsf(v.w)), m));
  }
  for (int off = 32; off; off >>= 1) m = fmaxf(m, __shfl_down(m, off, 64));
  __shared__ float sm[4];
  int lane = threadIdx.x & 63, wv = threadIdx.x >> 6;
  if (!lane) sm[wv] = m;
  __syncthreads();
  if (threadIdx.x == 0)
    atomicMax(sc + seg, __float_as_uint(fmaxf(fmaxf(sm[0], sm[1]), fmaxf(sm[2], sm[3]))));
}

// ---------------- weight quant + relayout: w[O][C][3][3] -> wq[O][khw*256+c] ----------------
__global__ __launch_bounds__(256) void quantw_kernel(const float* __restrict__ w, US* __restrict__ wq,
                                                     const unsigned* __restrict__ sc, int sidx) {
  int j = blockIdx.x * 256 + threadIdx.x;
  if (j >= 256 * 2304) return;
  float s = u2f(sc[sidx]) / 127.f + 1e-12f;
  int o = j / 2304, k = j - o * 2304, khw = k >> 8, c = k & 255;
  float q = fminf(fmaxf(rintf(w[(size_t)(o * 256 + c) * 9 + khw] / s), -128.f), 127.f);
  wq[j] = f2bf(q);
}

// ---------------- x quant + NCHW -> halo'd NHWC bf16 ----------------
__global__ __launch_bounds__(256) void quantx_kernel(const float* __restrict__ x,
                                                     US* __restrict__ halo,
                                                     const unsigned* __restrict__ sc) {
  int n = blockIdx.x >> 5, h = blockIdx.x & 31;
  float s = u2f(sc[0]) / 127.f + 1e-12f;
  __shared__ float lds[32 * 257];
  const float* src = x + (size_t)n * 256 * 1024 + h * 32;
  int t = threadIdx.x;
  int wloc = t & 31, crow = t >> 5;
  for (int cc = 0; cc < 256; cc += 8) {
    int c = cc + crow;
    lds[wloc * 257 + c] = src[(size_t)c * 1024 + wloc];
  }
  __syncthreads();
  US* dst = halo + ((size_t)((n * 34 + h + 1) * 34) + 1) * 256;
  for (int w_ = 0; w_ < 32; ++w_) {
    float v = lds[w_ * 257 + t];
    float q = fminf(fmaxf(rintf(v / s), -128.f), 127.f);
    dst[(size_t)w_ * 256 + t] = f2bf(q);
  }
}

// ---------------- 256x256 deep-pipelined implicit-GEMM conv ----------------
// BM=BN=256, K-chunk=32 per phase, 72 phases, 4 LDS regions (lookahead 3),
// counted vmcnt(8) (never 0 in main loop), T2 row-pair XOR swizzle, T5 setprio.
// MODE 0: A = act pixels (M), B = weights (N), out[p*256+o]; BN1 partial stats
// MODE 1: A = weights (M=o), B = act pixels (N), out[o*65536+p]; BN2 partial stats
template <int MODE>
__global__ __launch_bounds__(512) void conv8_kernel(const US* __restrict__ aptr,
                                                    const US* __restrict__ bptr,
                                                    float* __restrict__ out,
                                                    const unsigned* __restrict__ sc,
                                                    float* __restrict__ part) {
  extern __shared__ char smem[];   // 4 regions x (A 16KB + B 16KB) = 128 KB
  const int tid = threadIdx.x, lane = tid & 63, wid = tid >> 6;
  const int wm = wid >> 2, wn = wid & 3;           // 2M x 4N waves
  int bid = blockIdx.x;
  bid = (bid & 7) * 32 + (bid >> 3);               // XCD-chunked swizzle (grid 256)
  const int pixBase = bid * 256;

  // ---- staging setup: per-thread 2 destination slots per side ----
  // LDS chunk layout [256 rows][32 k] packed as row-pairs with slot XOR:
  // byte(row,k) = (row>>1)*128 + (((((row&1)<<2)|(k>>3)) ^ ((row>>1)&7))<<4) + (k&7)*2
  long gA[2], gB[2];
  int ldst[2];
#pragma unroll
  for (int j = 0; j < 2; ++j) {
    int d = tid * 16 + j * 8192;
    int rp = d >> 7, s = (d >> 4) & 7, sp = s ^ (rp & 7);
    int row = rp * 2 + (sp >> 2), kl = (sp & 3) * 8;
    ldst[j] = d;
    int p = pixBase + row;
    int n = p >> 10, h = (p >> 5) & 31, w_ = p & 31;
    long ghalo = (long)((n * 34 + h) * 34 + w_) * 512 + kl * 2;
    long gwt = (long)row * 4608 + kl * 2;
    if (MODE == 0) { gA[j] = ghalo; gB[j] = gwt; }
    else           { gA[j] = gwt;  gB[j] = ghalo; }
  }

  // ---- fragment LDS byte offsets (constant across phases) ----
  const int g = lane >> 4, l15 = lane & 15;
  int aOff[8], bOff[4];
#pragma unroll
  for (int m = 0; m < 8; ++m) {
    int row = wm * 128 + m * 16 + l15; int rp = row >> 1;
    aOff[m] = rp * 128 + ((((((row & 1) << 2) | g)) ^ (rp & 7)) << 4);
  }
#pragma unroll
  for (int n = 0; n < 4; ++n) {
    int row = wn * 64 + n * 16 + l15; int rp = row >> 1;
    bOff[n] = rp * 128 + ((((((row & 1) << 2) | g)) ^ (rp & 7)) << 4);
  }

  const char* ac = (const char*)aptr;
  const char* bc = (const char*)bptr;
  char* lds = smem;

  auto stage = [&](int P) {
    int cblk = P / 9, khw = P - cblk * 9;
    int kh = khw / 3, kw = khw - kh * 3;
    long uH = (long)(kh * 34 + kw) * 512 + cblk * 64;
    long uW = (long)khw * 512 + cblk * 64;
    long uA = (MODE == 0) ? uH : uW;
    long uB = (MODE == 0) ? uW : uH;
    char* rb = lds + (P & 3) * 32768;
    async16(ac + gA[0] + uA, rb + ldst[0]);
    async16(ac + gA[1] + uA, rb + ldst[1]);
    async16(bc + gB[0] + uB, rb + 16384 + ldst[0]);
    async16(bc + gB[1] + uB, rb + 16384 + ldst[1]);
  };

  f32x4 acc[8][4];
#pragma unroll
  for (int m = 0; m < 8; ++m)
#pragma unroll
    for (int n = 0; n < 4; ++n)
#pragma unroll
      for (int r = 0; r < 4; ++r) acc[m][n][r] = 0.f;

  // prologue: chunks 0..2 in flight; wait chunk 0 (leave 8 = chunks 1,2)
  stage(0); stage(1); stage(2);
  asm volatile("s_waitcnt vmcnt(8)" ::: "memory");
  asm volatile("s_barrier" ::: "memory");

  for (int P = 0; P < 72; ++P) {
    if (P < 69) stage(P + 3);
    const char* rb = lds + (P & 3) * 32768;
    bf16x8 a[8], b[4];
#pragma unroll
    for (int m = 0; m < 8; ++m) a[m] = *(const bf16x8*)(rb + aOff[m]);
#pragma unroll
    for (int n = 0; n < 4; ++n) b[n] = *(const bf16x8*)(rb + 16384 + bOff[n]);
    __builtin_amdgcn_s_setprio(1);
#pragma unroll
    for (int m = 0; m < 8; ++m)
#pragma unroll
      for (int n = 0; n < 4; ++n)
        acc[m][n] = __builtin_amdgcn_mfma_f32_16x16x32_bf16(a[m], b[n], acc[m][n], 0, 0, 0);
    __builtin_amdgcn_s_setprio(0);
    if (P < 69)      asm volatile("s_waitcnt vmcnt(8)" ::: "memory");
    else if (P == 69) asm volatile("s_waitcnt vmcnt(4)" ::: "memory");
    else if (P == 70) asm volatile("s_waitcnt vmcnt(0)" ::: "memory");
    if (P < 71) asm volatile("s_barrier" ::: "memory");
  }
  __syncthreads();

  if constexpr (MODE == 0) {
    const float s = (u2f(sc[0]) / 127.f + 1e-12f) * (u2f(sc[1]) / 127.f + 1e-12f);
    float vs[4], vss[4], vmx[4], vmn[4];
#pragma unroll
    for (int n = 0; n < 4; ++n) { vs[n] = 0.f; vss[n] = 0.f; vmx[n] = -3.4e38f; vmn[n] = 3.4e38f; }
#pragma unroll
    for (int m = 0; m < 8; ++m) {
      int p0 = pixBase + wm * 128 + m * 16 + g * 4;
#pragma unroll
      for (int n = 0; n < 4; ++n) {
        int ch = wn * 64 + n * 16 + l15;
#pragma unroll
        for (int r = 0; r < 4; ++r) {
          float v = acc[m][n][r] * s;
          out[(size_t)(p0 + r) * 256 + ch] = v;
          vs[n] += v; vss[n] += v * v;
          vmx[n] = fmaxf(vmx[n], v); vmn[n] = fminf(vmn[n], v);
        }
      }
    }
#pragma unroll
    for (int off = 16; off <= 32; off <<= 1)
#pragma unroll
      for (int n = 0; n < 4; ++n) {
        vs[n] += __shfl_xor(vs[n], off, 64);
        vss[n] += __shfl_xor(vss[n], off, 64);
        vmx[n] = fmaxf(vmx[n], __shfl_xor(vmx[n], off, 64));
        vmn[n] = fminf(vmn[n], __shfl_xor(vmn[n], off, 64));
      }
    float* S0 = (float*)smem;           // [2 wm][256 ch] x4 stats
    float* S1 = S0 + 512;
    float* S2 = S0 + 1024;
    float* S3 = S0 + 1536;
    if (lane < 16) {
#pragma unroll
      for (int n = 0; n < 4; ++n) {
        int ch = wn * 64 + n * 16 + l15;
        S0[wm * 256 + ch] = vs[n]; S1[wm * 256 + ch] = vss[n];
        S2[wm * 256 + ch] = vmx[n]; S3[wm * 256 + ch] = vmn[n];
      }
    }
    __syncthreads();
    if (tid < 256) {
      int idx = bid * 256 + tid;
      part[idx]          = S0[tid] + S0[256 + tid];
      part[65536 + idx]  = S1[tid] + S1[256 + tid];
      part[131072 + idx] = fmaxf(S2[tid], S2[256 + tid]);
      part[196608 + idx] = fminf(S3[tid], S3[256 + tid]);
    }
  } else {
    const float s = (u2f(sc[3]) / 255.f + 1e-12f) * (u2f(sc[2]) / 127.f + 1e-12f);
    float* SS = (float*)smem;           // [4 wn][256 o]
    float* SQ = SS + 1024;
#pragma unroll
    for (int m = 0; m < 8; ++m) {
      float sr[4], sq[4];
#pragma unroll
      for (int r = 0; r < 4; ++r) { sr[r] = 0.f; sq[r] = 0.f; }
      int o0 = wm * 128 + m * 16 + g * 4;
#pragma unroll
      for (int n = 0; n < 4; ++n) {
        int p = pixBase + wn * 64 + n * 16 + l15;
#pragma unroll
        for (int r = 0; r < 4; ++r) {
          float v = acc[m][n][r] * s;
          out[(size_t)(o0 + r) * 65536 + p] = v;
          sr[r] += v; sq[r] += v * v;
        }
      }
#pragma unroll
      for (int off = 1; off <= 8; off <<= 1)
#pragma unroll
        for (int r = 0; r < 4; ++r) {
          sr[r] += __shfl_xor(sr[r], off, 64);
          sq[r] += __shfl_xor(sq[r], off, 64);
        }
      if (l15 == 0) {
#pragma unroll
        for (int r = 0; r < 4; ++r) {
          SS[wn * 256 + o0 + r] = sr[r];
          SQ[wn * 256 + o0 + r] = sq[r];
        }
      }
    }
    __syncthreads();
    if (tid < 256) {
      float a = 0.f, b = 0.f;
#pragma unroll
      for (int w = 0; w < 4; ++w) { a += SS[w * 256 + tid]; b += SQ[w * 256 + tid]; }
      part[bid * 256 + tid] = a;
      part[65536 + bid * 256 + tid] = b;
    }
  }
}

// ---------------- BN1 finalize: 256 partials/ch -> bnA,bnB + relu-max -> sc[3] ----------------
__global__ __launch_bounds__(256) void bn1fin_kernel(const float* __restrict__ part,
                                                     const float* __restrict__ g,
                                                     const float* __restrict__ be,
                                                     float* __restrict__ bnA, float* __restrict__ bnB,
                                                     unsigned* __restrict__ sc) {
  int o0 = blockIdx.x * 32;
  int t = threadIdx.x, oc = t & 31, mq = t >> 5;   // 8 groups x 32 blocks
  float s = 0.f, ss = 0.f, mx = -3.4e38f, mn = 3.4e38f;
  for (int j = 0; j < 32; ++j) {
    int i = (mq * 32 + j) * 256 + o0 + oc;
    s += part[i]; ss += part[65536 + i];
    mx = fmaxf(mx, part[131072 + i]); mn = fminf(mn, part[196608 + i]);
  }
  __shared__ float red[4][8][32];
  red[0][mq][oc] = s; red[1][mq][oc] = ss; red[2][mq][oc] = mx; red[3][mq][oc] = mn;
  __syncthreads();
  if (t < 32) {
    s = 0.f; ss = 0.f; mx = -3.4e38f; mn = 3.4e38f;
    for (int q = 0; q < 8; ++q) {
      s += red[0][q][t]; ss += red[1][q][t];
      mx = fmaxf(mx, red[2][q][t]); mn = fminf(mn, red[3][q][t]);
    }
    float mean = s * (1.f / 65536.f);
    float var = fmaxf(ss * (1.f / 65536.f) - mean * mean, 0.f);
    int o = o0 + t;
    float a = g[o] * rsqrtf(var + 1e-5f);
    float b2 = be[o] - mean * a;
    bnA[o] = a; bnB[o] = b2;
    float m = fmaxf(fmaxf(a * mx + b2, a * mn + b2), 0.f);
    atomicMax(sc + 3, __float_as_uint(m));
  }
}

// ---------------- BN2 finalize ----------------
__global__ __launch_bounds__(256) void bn2fin_kernel(const float* __restrict__ part,
                                                     const float* __restrict__ g,
                                                     const float* __restrict__ be,
                                                     float* __restrict__ bnA2, float* __restrict__ bnB2) {
  int o0 = blockIdx.x * 32;
  int t = threadIdx.x, oc = t & 31, mq = t >> 5;
  float s = 0.f, ss = 0.f;
  for (int j = 0; j < 32; ++j) {
    int i = (mq * 32 + j) * 256 + o0 + oc;
    s += part[i]; ss += part[65536 + i];
  }
  __shared__ float red[2][8][32];
  red[0][mq][oc] = s; red[1][mq][oc] = ss;
  __syncthreads();
  if (t < 32) {
    s = 0.f; ss = 0.f;
    for (int q = 0; q < 8; ++q) { s += red[0][q][t]; ss += red[1][q][t]; }
    float mean = s * (1.f / 65536.f);
    float var = fmaxf(ss * (1.f / 65536.f) - mean * mean, 0.f);
    int o = o0 + t;
    float a = g[o] * rsqrtf(var + 1e-5f);
    bnA2[o] = a;
    bnB2[o] = be[o] - mean * a;
  }
}

// ---------------- BN1 apply + ReLU + unsigned quant -> halo ----------------
__global__ __launch_bounds__(256) void apply_kernel(const float* __restrict__ y,
                                                    const float* __restrict__ bnA,
                                                    const float* __restrict__ bnB,
                                                    const unsigned* __restrict__ sc,
                                                    US* __restrict__ halo) {
  int t = threadIdx.x;
  int c4 = (t & 63) * 4;
  int psub = t >> 6;
  float s2 = u2f(sc[3]) / 255.f + 1e-12f;
  float4 a = *(const float4*)(bnA + c4);
  float4 b = *(const float4*)(bnB + c4);
  int p0 = blockIdx.x * 16 + psub;
  for (int j = 0; j < 4; ++j) {
    int p = p0 + j * 4;
    float4 v = *(const float4*)(y + (size_t)p * 256 + c4);
    ushort4 q;
    q.x = f2bf(fminf(fmaxf(rintf(fmaxf(a.x * v.x + b.x, 0.f) / s2), 0.f), 255.f));
    q.y = f2bf(fminf(fmaxf(rintf(fmaxf(a.y * v.y + b.y, 0.f) / s2), 0.f), 255.f));
    q.z = f2bf(fminf(fmaxf(rintf(fmaxf(a.z * v.z + b.z, 0.f) / s2), 0.f), 255.f));
    q.w = f2bf(fminf(fmaxf(rintf(fmaxf(a.w * v.w + b.w, 0.f) / s2), 0.f), 255.f));
    int n = p >> 10, h = (p >> 5) & 31, w_ = p & 31;
    *(ushort4*)(halo + ((size_t)((n * 34 + h + 1) * 34) + (w_ + 1)) * 256 + c4) = q;
  }
}

// ---------------- BN2 + residual + ReLU -> NCHW out ----------------
__global__ __launch_bounds__(256) void final_kernel(const float* __restrict__ y2,
                                                    const float* __restrict__ x,
                                                    const float* __restrict__ bnA2,
                                                    const float* __restrict__ bnB2,
                                                    float* __restrict__ out) {
  int tid = blockIdx.x * 256 + threadIdx.x;
  for (int i = tid; i < 4194304; i += 1048576) {
    int e = i << 2;
    int o = (e >> 10) & 255;
    int n = e >> 18, hw = e & 1023;
    float4 v = *(const float4*)(y2 + (((size_t)o << 16) + (n << 10) + hw));
    float4 xr = ((const float4*)x)[i];
    float a = bnA2[o], b = bnB2[o];
    float4 r;
    r.x = fmaxf(a * v.x + b + xr.x, 0.f);
    r.y = fmaxf(a * v.y + b + xr.y, 0.f);
    r.z = fmaxf(a * v.z + b + xr.z, 0.f);
    r.w = fmaxf(a * v.w + b + xr.w, 0.f);
    ((float4*)out)[i] = r;
  }
}

extern "C" void kernel_launch(void* const* d_in, const int* in_sizes, int n_in,
                              void* d_out, int out_size, void* d_ws, size_t ws_size,
                              hipStream_t stream) {
  const float* x  = (const float*)d_in[0];
  const float* w1 = (const float*)d_in[1];
  const float* g1 = (const float*)d_in[2];
  const float* b1 = (const float*)d_in[3];
  const float* w2 = (const float*)d_in[4];
  const float* g2 = (const float*)d_in[5];
  const float* b2 = (const float*)d_in[6];
  float* out = (float*)d_out;
  char* ws = (char*)d_ws;

  unsigned* sc = (unsigned*)ws;                    // sc[0..2]=absmax, sc[3]=relu-max
  float* bnA   = (float*)(ws + 8192);
  float* bnB   = (float*)(ws + 12288);
  float* bnA2  = (float*)(ws + 16384);
  float* bnB2  = (float*)(ws + 20480);
  float* part  = (float*)(ws + 24576);             // 1 MB (4 slabs x 256x256)
  US* wq1  = (US*)(ws + 24576 + 2097152);
  US* wq2  = (US*)(ws + 24576 + 2097152 + 1179648);
  US* halo = (US*)(ws + 24576 + 2097152 + 2 * 1179648);                       // 36.1 MB
  float* convb = (float*)(ws + 24576 + 2097152 + 2 * 1179648 + 37879808);     // 64 MB

  hipFuncSetAttribute((const void*)(conv8_kernel<0>), hipFuncAttributeMaxDynamicSharedMemorySize, 131072);
  hipFuncSetAttribute((const void*)(conv8_kernel<1>), hipFuncAttributeMaxDynamicSharedMemorySize, 131072);

  hipMemsetAsync(sc, 0, 64, stream);
  hipMemsetAsync(halo, 0, 37879808, stream);

  absmax3_kernel<<<1920, 256, 0, stream>>>(x, w1, w2, sc);
  quantw_kernel<<<2304, 256, 0, stream>>>(w1, wq1, sc, 1);
  quantw_kernel<<<2304, 256, 0, stream>>>(w2, wq2, sc, 2);
  quantx_kernel<<<2048, 256, 0, stream>>>(x, halo, sc);
  conv8_kernel<0><<<256, 512, 131072, stream>>>(halo, wq1, convb, sc, part);
  bn1fin_kernel<<<8, 256, 0, stream>>>(part, g1, b1, bnA, bnB, sc);
  apply_kernel<<<4096, 256, 0, stream>>>(convb, bnA, bnB, sc, halo);
  conv8_kernel<1><<<256, 512, 131072, stream>>>(wq2, halo, convb, sc, part);
  bn2fin_kernel<<<8, 256, 0, stream>>>(part, g2, b2, bnA2, bnB2);
  final_kernel<<<4096, 256, 0, stream>>>(convb, x, bnA2, bnB2, out);
}

// Round 4
// 332.399 us; speedup vs baseline: 1.5182x; 1.1043x over previous
//
#include <hip/hip_runtime.h>

typedef __attribute__((ext_vector_type(4))) int i32x4;
typedef __attribute__((ext_vector_type(4))) float f32x4;

typedef __attribute__((address_space(1))) unsigned int uglobal;
typedef __attribute__((address_space(3))) unsigned int ulocal;

__device__ __forceinline__ void async16(const void* g, void* l) {
  __builtin_amdgcn_global_load_lds((const uglobal*)g, (ulocal*)l, 16, 0, 0);
}
__device__ __forceinline__ float u2f(unsigned u) { return __uint_as_float(u); }

// ---------------- fused absmax over x, w1, w2 ----------------
__global__ __launch_bounds__(256) void absmax3_kernel(const float* __restrict__ x,
                                                      const float* __restrict__ w1,
                                                      const float* __restrict__ w2,
                                                      unsigned* __restrict__ sc) {
  int b = blockIdx.x;
  const float* src; int n4, b0, nb, seg;
  if (b < 1792)      { src = x;  n4 = 4194304; b0 = 0;    nb = 1792; seg = 0; }
  else if (b < 1856) { src = w1; n4 = 147456;  b0 = 1792; nb = 64;   seg = 1; }
  else               { src = w2; n4 = 147456;  b0 = 1856; nb = 64;   seg = 2; }
  float m = 0.f;
  int stride = nb * 256;
  for (int i = (b - b0) * 256 + threadIdx.x; i < n4; i += stride) {
    float4 v = ((const float4*)src)[i];
    m = fmaxf(fmaxf(fabsf(v.x), fabsf(v.y)), fmaxf(fmaxf(fabsf(v.z), fabsf(v.w)), m));
  }
  for (int off = 32; off; off >>= 1) m = fmaxf(m, __shfl_down(m, off, 64));
  __shared__ float sm[4];
  int lane = threadIdx.x & 63, wv = threadIdx.x >> 6;
  if (!lane) sm[wv] = m;
  __syncthreads();
  if (threadIdx.x == 0)
    atomicMax(sc + seg, __float_as_uint(fmaxf(fmaxf(sm[0], sm[1]), fmaxf(sm[2], sm[3]))));
}

// ---------------- weight quant (both) + relayout -> int8 wq[O][tap*256+c] ----------------
__global__ __launch_bounds__(256) void quantw_kernel(const float* __restrict__ w1,
                                                     const float* __restrict__ w2,
                                                     signed char* __restrict__ wq1,
                                                     signed char* __restrict__ wq2,
                                                     const unsigned* __restrict__ sc) {
  int b = blockIdx.x;
  int t2 = b >= 2304;
  const float* w = t2 ? w2 : w1;
  signed char* wq = t2 ? wq2 : wq1;
  float s = u2f(sc[1 + t2]) / 127.f + 1e-12f;
  int j = (b - t2 * 2304) * 256 + threadIdx.x;
  int o = j / 2304, k = j - o * 2304, tap = k >> 8, c = k & 255;
  float q = fminf(fmaxf(rintf(w[(size_t)(o * 256 + c) * 9 + tap] / s), -128.f), 127.f);
  wq[j] = (signed char)q;
}

// ---------------- per-o 128*sum(w2) for the unsigned-offset correction ----------------
__global__ __launch_bounds__(64) void tapsum_kernel(const signed char* __restrict__ wq2,
                                                    int* __restrict__ csumT) {
  int o = blockIdx.x;
  const int* row = (const int*)(wq2 + (size_t)o * 2304);
  int s = 0;
  for (int i = threadIdx.x; i < 576; i += 64) {
    int v = row[i];
    s += (int)(signed char)(v) + (int)(signed char)(v >> 8) +
         (int)(signed char)(v >> 16) + (int)(signed char)(v >> 24);
  }
  for (int off = 32; off; off >>= 1) s += __shfl_down(s, off, 64);
  if (threadIdx.x == 0) csumT[o] = 128 * s;
}

// ---------------- x quant + NCHW -> halo'd NHWC int8 ----------------
__global__ __launch_bounds__(256) void quantx_kernel(const float* __restrict__ x,
                                                     signed char* __restrict__ halo,
                                                     const unsigned* __restrict__ sc) {
  int n = blockIdx.x >> 5, h = blockIdx.x & 31;
  float s = u2f(sc[0]) / 127.f + 1e-12f;
  __shared__ float lds[32 * 257];
  const float* src = x + (size_t)n * 262144 + h * 32;
  int t = threadIdx.x;
  int wloc = t & 31, crow = t >> 5;
  for (int cc = 0; cc < 256; cc += 8) {
    int c = cc + crow;
    lds[wloc * 257 + c] = src[(size_t)c * 1024 + wloc];
  }
  __syncthreads();
  signed char* dst = halo + ((size_t)((n * 34 + h + 1) * 34) + 1) * 256;
  int c4 = (t & 63) * 4, wsub = t >> 6;
  for (int j = 0; j < 8; ++j) {
    int w_ = wsub * 8 + j;
    char4 q;
    q.x = (signed char)fminf(fmaxf(rintf(lds[w_ * 257 + c4 + 0] / s), -128.f), 127.f);
    q.y = (signed char)fminf(fmaxf(rintf(lds[w_ * 257 + c4 + 1] / s), -128.f), 127.f);
    q.z = (signed char)fminf(fmaxf(rintf(lds[w_ * 257 + c4 + 2] / s), -128.f), 127.f);
    q.w = (signed char)fminf(fmaxf(rintf(lds[w_ * 257 + c4 + 3] / s), -128.f), 127.f);
    *(char4*)(dst + (size_t)w_ * 256 + c4) = q;
  }
}

// ---------------- 256x256 deep-pipelined int8 implicit-GEMM conv ----------------
// K-chunk=64 (one tap x 64 channels), 36 phases, 4 LDS regions, lookahead 3,
// counted vmcnt(8), row-pair XOR swizzle, setprio, LDS-transpose float4 epilogue.
// MODE 0: A=act pixels, B=weights, out[p*256+o], BN1 stats (sum/ss/max/min)
// MODE 1: A=weights(o), B=act pixels, out[o*65536+p], +128*sum(w) correction, BN2 stats
template <int MODE>
__global__ __launch_bounds__(512) void conv_i8_kernel(const signed char* __restrict__ aptr,
                                                      const signed char* __restrict__ bptr,
                                                      float* __restrict__ out,
                                                      const unsigned* __restrict__ sc,
                                                      float* __restrict__ part,
                                                      const int* __restrict__ csumT) {
  extern __shared__ char smem[];  // 147456: K-regions [0,128K), transpose [0,139264), stats [139264,147456)
  const int tid = threadIdx.x, lane = tid & 63, wid = tid >> 6;
  const int wm = wid >> 2, wn = wid & 3;     // 2M x 4N waves, per-wave 128x64
  int bid = blockIdx.x;
  bid = (bid & 7) * 32 + (bid >> 3);         // XCD-chunked swizzle (grid 256)
  const int pixBase = bid * 256;

  // staging: per-thread 2 x 16B slots per side; LDS layout
  // byte(row,k) = (row>>1)*128 + ((((row&1)<<2)|(k>>4)) ^ ((row>>1)&7))*16 + (k&15)
  long gA[2], gB[2];
  int ldst[2];
#pragma unroll
  for (int j = 0; j < 2; ++j) {
    int d = tid * 16 + j * 8192;
    int rp = d >> 7, s5 = (d >> 4) & 7, sp = s5 ^ (rp & 7);
    int row = rp * 2 + (sp >> 2), kc = (sp & 3) * 16;
    ldst[j] = d;
    int p = pixBase + row;
    int n = p >> 10, h = (p >> 5) & 31, w_ = p & 31;
    long ghalo = (long)((n * 34 + h) * 34 + w_) * 256 + kc;
    long gwt = (long)row * 2304 + kc;
    gA[j] = (MODE == 0) ? ghalo : gwt;
    gB[j] = (MODE == 0) ? gwt : ghalo;
  }

  const int g = lane >> 4, l15 = lane & 15;
  int aOff[8], bOff[4];
#pragma unroll
  for (int m = 0; m < 8; ++m) {
    int row = wm * 128 + m * 16 + l15; int rp = row >> 1;
    aOff[m] = rp * 128 + (((((row & 1) << 2) | g) ^ (rp & 7)) << 4);
  }
#pragma unroll
  for (int n = 0; n < 4; ++n) {
    int row = wn * 64 + n * 16 + l15; int rp = row >> 1;
    bOff[n] = rp * 128 + (((((row & 1) << 2) | g) ^ (rp & 7)) << 4);
  }

  const char* ac = (const char*)aptr;
  const char* bc = (const char*)bptr;
  char* lds = smem;

  auto stage = [&](int P) {
    int cblk = P / 9, tap = P - cblk * 9;    // c-outer, tap-inner (L2 reuse 1 phase apart)
    int kh = tap / 3, kw = tap - kh * 3;
    long uH = (long)(kh * 34 + kw) * 256 + cblk * 64;
    long uW = (long)tap * 256 + cblk * 64;
    long uA = (MODE == 0) ? uH : uW;
    long uB = (MODE == 0) ? uW : uH;
    char* rb = lds + (P & 3) * 32768;
    async16(ac + gA[0] + uA, rb + ldst[0]);
    async16(ac + gA[1] + uA, rb + ldst[1]);
    async16(bc + gB[0] + uB, rb + 16384 + ldst[0]);
    async16(bc + gB[1] + uB, rb + 16384 + ldst[1]);
  };

  i32x4 acc[8][4];
#pragma unroll
  for (int m = 0; m < 8; ++m)
#pragma unroll
    for (int n = 0; n < 4; ++n)
#pragma unroll
      for (int r = 0; r < 4; ++r) acc[m][n][r] = 0;

  stage(0); stage(1); stage(2);
  asm volatile("s_waitcnt vmcnt(8)" ::: "memory");
  asm volatile("s_barrier" ::: "memory");

  for (int P = 0; P < 36; ++P) {
    if (P < 33) stage(P + 3);
    const char* rb = lds + (P & 3) * 32768;
    i32x4 a[8], b[4];
#pragma unroll
    for (int m = 0; m < 8; ++m) a[m] = *(const i32x4*)(rb + aOff[m]);
#pragma unroll
    for (int n = 0; n < 4; ++n) b[n] = *(const i32x4*)(rb + 16384 + bOff[n]);
    __builtin_amdgcn_s_setprio(1);
#pragma unroll
    for (int m = 0; m < 8; ++m)
#pragma unroll
      for (int n = 0; n < 4; ++n)
        acc[m][n] = __builtin_amdgcn_mfma_i32_16x16x64_i8(a[m], b[n], acc[m][n], 0, 0, 0);
    __builtin_amdgcn_s_setprio(0);
    if (P < 33)       asm volatile("s_waitcnt vmcnt(8)" ::: "memory");
    else if (P == 33) asm volatile("s_waitcnt vmcnt(4)" ::: "memory");
    else if (P == 34) asm volatile("s_waitcnt vmcnt(0)" ::: "memory");
    if (P < 35) asm volatile("s_barrier" ::: "memory");
  }
  __syncthreads();

  float* twr = (float*)(smem + wid * 17408);   // per-wave 64x68 f32 transpose pad

  if constexpr (MODE == 0) {
    const float s = (u2f(sc[0]) / 127.f + 1e-12f) * (u2f(sc[1]) / 127.f + 1e-12f);
    float vs[4], vss[4], vmx[4], vmn[4];
#pragma unroll
    for (int n = 0; n < 4; ++n) { vs[n] = 0.f; vss[n] = 0.f; vmx[n] = -3.4e38f; vmn[n] = 3.4e38f; }
#pragma unroll
    for (int half = 0; half < 2; ++half) {
#pragma unroll
      for (int m2 = 0; m2 < 4; ++m2) {
        int m = half * 4 + m2;
#pragma unroll
        for (int n = 0; n < 4; ++n)
#pragma unroll
          for (int r = 0; r < 4; ++r) {
            float v = (float)acc[m][n][r] * s;
            vs[n] += v; vss[n] += v * v;
            vmx[n] = fmaxf(vmx[n], v); vmn[n] = fminf(vmn[n], v);
            twr[(m2 * 16 + g * 4 + r) * 68 + n * 16 + l15] = v;
          }
      }
#pragma unroll
      for (int it = 0; it < 16; ++it) {
        int i = it * 64 + lane;
        int row = i >> 4, c4 = (i & 15) << 2;
        float4 v4 = *(const float4*)(twr + row * 68 + c4);
        int p = pixBase + wm * 128 + half * 64 + row;
        *(float4*)(out + (size_t)p * 256 + wn * 64 + c4) = v4;
      }
    }
#pragma unroll
    for (int off = 16; off <= 32; off <<= 1)
#pragma unroll
      for (int n = 0; n < 4; ++n) {
        vs[n] += __shfl_xor(vs[n], off, 64);
        vss[n] += __shfl_xor(vss[n], off, 64);
        vmx[n] = fmaxf(vmx[n], __shfl_xor(vmx[n], off, 64));
        vmn[n] = fminf(vmn[n], __shfl_xor(vmn[n], off, 64));
      }
    __syncthreads();
    float* S0 = (float*)(smem + 139264);
    float* S1 = S0 + 512; float* S2 = S0 + 1024; float* S3 = S0 + 1536;
    if (lane < 16) {
#pragma unroll
      for (int n = 0; n < 4; ++n) {
        int ch = wn * 64 + n * 16 + l15;
        S0[wm * 256 + ch] = vs[n]; S1[wm * 256 + ch] = vss[n];
        S2[wm * 256 + ch] = vmx[n]; S3[wm * 256 + ch] = vmn[n];
      }
    }
    __syncthreads();
    if (tid < 256) {
      int idx = bid * 256 + tid;
      part[idx]          = S0[tid] + S0[256 + tid];
      part[65536 + idx]  = S1[tid] + S1[256 + tid];
      part[131072 + idx] = fmaxf(S2[tid], S2[256 + tid]);
      part[196608 + idx] = fminf(S3[tid], S3[256 + tid]);
    }
  } else {
    const float s = (u2f(sc[3]) / 255.f + 1e-12f) * (u2f(sc[2]) / 127.f + 1e-12f);
    float* SS = (float*)(smem + 139264);   // [4 wn][256 o]
    float* SQ = SS + 1024;
#pragma unroll
    for (int half = 0; half < 2; ++half) {
#pragma unroll
      for (int m2 = 0; m2 < 4; ++m2) {
        int m = half * 4 + m2;
        int o0 = wm * 128 + half * 64 + m2 * 16 + g * 4;
        i32x4 tc = *(const i32x4*)(csumT + o0);
        float sr[4] = {0.f, 0.f, 0.f, 0.f}, sq[4] = {0.f, 0.f, 0.f, 0.f};
#pragma unroll
        for (int n = 0; n < 4; ++n)
#pragma unroll
          for (int r = 0; r < 4; ++r) {
            float v = (float)(acc[m][n][r] + tc[r]) * s;
            sr[r] += v; sq[r] += v * v;
            twr[(m2 * 16 + g * 4 + r) * 68 + n * 16 + l15] = v;
          }
#pragma unroll
        for (int off = 1; off <= 8; off <<= 1)
#pragma unroll
          for (int r = 0; r < 4; ++r) {
            sr[r] += __shfl_xor(sr[r], off, 64);
            sq[r] += __shfl_xor(sq[r], off, 64);
          }
        if (l15 == 0) {
#pragma unroll
          for (int r = 0; r < 4; ++r) {
            SS[wn * 256 + o0 + r] = sr[r];
            SQ[wn * 256 + o0 + r] = sq[r];
          }
        }
      }
#pragma unroll
      for (int it = 0; it < 16; ++it) {
        int i = it * 64 + lane;
        int row = i >> 4, c4 = (i & 15) << 2;
        float4 v4 = *(const float4*)(twr + row * 68 + c4);
        int o = wm * 128 + half * 64 + row;
        *(float4*)(out + (size_t)o * 65536 + pixBase + wn * 64 + c4) = v4;
      }
    }
    __syncthreads();
    if (tid < 256) {
      float a = 0.f, b = 0.f;
#pragma unroll
      for (int w = 0; w < 4; ++w) { a += SS[w * 256 + tid]; b += SQ[w * 256 + tid]; }
      part[bid * 256 + tid] = a;
      part[65536 + bid * 256 + tid] = b;
    }
  }
}

// ---------------- BN1 finalize ----------------
__global__ __launch_bounds__(256) void bn1fin_kernel(const float* __restrict__ part,
                                                     const float* __restrict__ g,
                                                     const float* __restrict__ be,
                                                     float* __restrict__ bnA, float* __restrict__ bnB,
                                                     unsigned* __restrict__ sc) {
  int o0 = blockIdx.x * 32;
  int t = threadIdx.x, oc = t & 31, mq = t >> 5;
  float s = 0.f, ss = 0.f, mx = -3.4e38f, mn = 3.4e38f;
  for (int j = 0; j < 32; ++j) {
    int i = (mq * 32 + j) * 256 + o0 + oc;
    s += part[i]; ss += part[65536 + i];
    mx = fmaxf(mx, part[131072 + i]); mn = fminf(mn, part[196608 + i]);
  }
  __shared__ float red[4][8][32];
  red[0][mq][oc] = s; red[1][mq][oc] = ss; red[2][mq][oc] = mx; red[3][mq][oc] = mn;
  __syncthreads();
  if (t < 32) {
    s = 0.f; ss = 0.f; mx = -3.4e38f; mn = 3.4e38f;
    for (int q = 0; q < 8; ++q) {
      s += red[0][q][t]; ss += red[1][q][t];
      mx = fmaxf(mx, red[2][q][t]); mn = fminf(mn, red[3][q][t]);
    }
    float mean = s * (1.f / 65536.f);
    float var = fmaxf(ss * (1.f / 65536.f) - mean * mean, 0.f);
    int o = o0 + t;
    float a = g[o] * rsqrtf(var + 1e-5f);
    float b2 = be[o] - mean * a;
    bnA[o] = a; bnB[o] = b2;
    float m = fmaxf(fmaxf(a * mx + b2, a * mn + b2), 0.f);
    atomicMax(sc + 3, __float_as_uint(m));
  }
}

// ---------------- BN2 finalize ----------------
__global__ __launch_bounds__(256) void bn2fin_kernel(const float* __restrict__ part,
                                                     const float* __restrict__ g,
                                                     const float* __restrict__ be,
                                                     float* __restrict__ bnA2, float* __restrict__ bnB2) {
  int o0 = blockIdx.x * 32;
  int t = threadIdx.x, oc = t & 31, mq = t >> 5;
  float s = 0.f, ss = 0.f;
  for (int j = 0; j < 32; ++j) {
    int i = (mq * 32 + j) * 256 + o0 + oc;
    s += part[i]; ss += part[65536 + i];
  }
  __shared__ float red[2][8][32];
  red[0][mq][oc] = s; red[1][mq][oc] = ss;
  __syncthreads();
  if (t < 32) {
    s = 0.f; ss = 0.f;
    for (int q = 0; q < 8; ++q) { s += red[0][q][t]; ss += red[1][q][t]; }
    float mean = s * (1.f / 65536.f);
    float var = fmaxf(ss * (1.f / 65536.f) - mean * mean, 0.f);
    int o = o0 + t;
    float a = g[o] * rsqrtf(var + 1e-5f);
    bnA2[o] = a;
    bnB2[o] = be[o] - mean * a;
  }
}

// ---------------- BN1 apply + ReLU + unsigned quant -> int8 halo (u-128, pad=-128) ----------------
__global__ __launch_bounds__(256) void apply_kernel(const float* __restrict__ y,
                                                    const float* __restrict__ bnA,
                                                    const float* __restrict__ bnB,
                                                    const unsigned* __restrict__ sc,
                                                    signed char* __restrict__ halo) {
  int t = threadIdx.x;
  int c4 = (t & 63) * 4;
  int psub = t >> 6;
  float s2 = u2f(sc[3]) / 255.f + 1e-12f;
  float4 a = *(const float4*)(bnA + c4);
  float4 b = *(const float4*)(bnB + c4);
  int p0 = blockIdx.x * 16 + psub;
  for (int j = 0; j < 4; ++j) {
    int p = p0 + j * 4;
    float4 v = *(const float4*)(y + (size_t)p * 256 + c4);
    char4 q;
    q.x = (signed char)((int)fminf(fmaxf(rintf(fmaxf(a.x * v.x + b.x, 0.f) / s2), 0.f), 255.f) - 128);
    q.y = (signed char)((int)fminf(fmaxf(rintf(fmaxf(a.y * v.y + b.y, 0.f) / s2), 0.f), 255.f) - 128);
    q.z = (signed char)((int)fminf(fmaxf(rintf(fmaxf(a.z * v.z + b.z, 0.f) / s2), 0.f), 255.f) - 128);
    q.w = (signed char)((int)fminf(fmaxf(rintf(fmaxf(a.w * v.w + b.w, 0.f) / s2), 0.f), 255.f) - 128);
    int n = p >> 10, h = (p >> 5) & 31, w_ = p & 31;
    *(char4*)(halo + ((size_t)((n * 34 + h + 1) * 34) + (w_ + 1)) * 256 + c4) = q;
  }
}

// ---------------- BN2 + residual + ReLU -> NCHW out ----------------
__global__ __launch_bounds__(256) void final_kernel(const float* __restrict__ y2,
                                                    const float* __restrict__ x,
                                                    const float* __restrict__ bnA2,
                                                    const float* __restrict__ bnB2,
                                                    float* __restrict__ out) {
  int tid = blockIdx.x * 256 + threadIdx.x;
  for (int i = tid; i < 4194304; i += 1048576) {
    int e = i << 2;
    int o = (e >> 10) & 255;
    int n = e >> 18, hw = e & 1023;
    float4 v = *(const float4*)(y2 + (((size_t)o << 16) + (n << 10) + hw));
    float4 xr = ((const float4*)x)[i];
    float a = bnA2[o], b = bnB2[o];
    float4 r;
    r.x = fmaxf(a * v.x + b + xr.x, 0.f);
    r.y = fmaxf(a * v.y + b + xr.y, 0.f);
    r.z = fmaxf(a * v.z + b + xr.z, 0.f);
    r.w = fmaxf(a * v.w + b + xr.w, 0.f);
    ((float4*)out)[i] = r;
  }
}

extern "C" void kernel_launch(void* const* d_in, const int* in_sizes, int n_in,
                              void* d_out, int out_size, void* d_ws, size_t ws_size,
                              hipStream_t stream) {
  const float* x  = (const float*)d_in[0];
  const float* w1 = (const float*)d_in[1];
  const float* g1 = (const float*)d_in[2];
  const float* b1 = (const float*)d_in[3];
  const float* w2 = (const float*)d_in[4];
  const float* g2 = (const float*)d_in[5];
  const float* b2 = (const float*)d_in[6];
  float* out = (float*)d_out;
  char* ws = (char*)d_ws;

  // workspace (~88.3 MB)
  unsigned* sc = (unsigned*)ws;                      // sc[0..2]=absmax, sc[3]=relu-max
  float* bnA   = (float*)(ws + 4096);
  float* bnB   = (float*)(ws + 8192);
  float* bnA2  = (float*)(ws + 12288);
  float* bnB2  = (float*)(ws + 16384);
  int*   csumT = (int*)(ws + 20480);                 // 1 KB
  float* part  = (float*)(ws + 24576);               // 1 MB (4 slabs x 256KB)
  signed char* wq1  = (signed char*)(ws + 24576 + 1048576);
  signed char* wq2  = wq1 + 589824;
  signed char* halo = wq2 + 589824;                  // 18,939,904 B (reused for conv2 input)
  float* convb = (float*)(ws + 24576 + 1048576 + 2 * 589824 + 18939904);  // 64 MB

  hipFuncSetAttribute((const void*)(conv_i8_kernel<0>), hipFuncAttributeMaxDynamicSharedMemorySize, 147456);
  hipFuncSetAttribute((const void*)(conv_i8_kernel<1>), hipFuncAttributeMaxDynamicSharedMemorySize, 147456);

  hipMemsetAsync(sc, 0, 64, stream);
  hipMemsetAsync(halo, 0, 18939904, stream);                 // pad=0 for signed conv1

  absmax3_kernel<<<1920, 256, 0, stream>>>(x, w1, w2, sc);
  quantw_kernel<<<4608, 256, 0, stream>>>(w1, w2, wq1, wq2, sc);
  tapsum_kernel<<<256, 64, 0, stream>>>(wq2, csumT);
  quantx_kernel<<<2048, 256, 0, stream>>>(x, halo, sc);
  conv_i8_kernel<0><<<256, 512, 147456, stream>>>(halo, wq1, convb, sc, part, csumT);
  bn1fin_kernel<<<8, 256, 0, stream>>>(part, g1, b1, bnA, bnB, sc);
  hipMemsetAsync(halo, 0x80, 18939904, stream);              // pad=-128 for offset conv2
  apply_kernel<<<4096, 256, 0, stream>>>(convb, bnA, bnB, sc, halo);
  conv_i8_kernel<1><<<256, 512, 147456, stream>>>(wq2, halo, convb, sc, part, csumT);
  bn2fin_kernel<<<8, 256, 0, stream>>>(part, g2, b2, bnA2, bnB2);
  final_kernel<<<4096, 256, 0, stream>>>(convb, x, bnA2, bnB2, out);
}

// Round 6
// 315.771 us; speedup vs baseline: 1.5981x; 1.0527x over previous
//
#include <hip/hip_runtime.h>

typedef __attribute__((ext_vector_type(4))) int i32x4;

typedef __attribute__((address_space(1))) unsigned int uglobal;
typedef __attribute__((address_space(3))) unsigned int ulocal;

__device__ __forceinline__ void async16(const void* g, void* l) {
  __builtin_amdgcn_global_load_lds((const uglobal*)g, (ulocal*)l, 16, 0, 0);
}
__device__ __forceinline__ float u2f(unsigned u) { return __uint_as_float(u); }

// ---------------- fused absmax over x, w1, w2 ----------------
__global__ __launch_bounds__(256) void absmax3_kernel(const float* __restrict__ x,
                                                      const float* __restrict__ w1,
                                                      const float* __restrict__ w2,
                                                      unsigned* __restrict__ sc) {
  int b = blockIdx.x;
  const float* src; int n4, b0, nb, seg;
  if (b < 1792)      { src = x;  n4 = 4194304; b0 = 0;    nb = 1792; seg = 0; }
  else if (b < 1856) { src = w1; n4 = 147456;  b0 = 1792; nb = 64;   seg = 1; }
  else               { src = w2; n4 = 147456;  b0 = 1856; nb = 64;   seg = 2; }
  float m = 0.f;
  int stride = nb * 256;
  for (int i = (b - b0) * 256 + threadIdx.x; i < n4; i += stride) {
    float4 v = ((const float4*)src)[i];
    m = fmaxf(fmaxf(fabsf(v.x), fabsf(v.y)), fmaxf(fmaxf(fabsf(v.z), fabsf(v.w)), m));
  }
  for (int off = 32; off; off >>= 1) m = fmaxf(m, __shfl_down(m, off, 64));
  __shared__ float sm[4];
  int lane = threadIdx.x & 63, wv = threadIdx.x >> 6;
  if (!lane) sm[wv] = m;
  __syncthreads();
  if (threadIdx.x == 0)
    atomicMax(sc + seg, __float_as_uint(fmaxf(fmaxf(sm[0], sm[1]), fmaxf(sm[2], sm[3]))));
}

// ---------------- weight quant + relayout + fused tapsum (one block per (which,o)) ----------------
__global__ __launch_bounds__(256) void quantw_kernel(const float* __restrict__ w1,
                                                     const float* __restrict__ w2,
                                                     signed char* __restrict__ wq1,
                                                     signed char* __restrict__ wq2,
                                                     const unsigned* __restrict__ sc,
                                                     int* __restrict__ csumT) {
  int b = blockIdx.x, which = b >> 8, o = b & 255, t = threadIdx.x;
  const float* w = which ? w2 : w1;
  signed char* wq = which ? wq2 : wq1;
  float s = u2f(sc[1 + which]) / 127.f + 1e-12f;
  __shared__ float lw[2304];
  for (int j = t; j < 2304; j += 256) lw[j] = w[(size_t)o * 2304 + j];
  __syncthreads();
  int ssum = 0;
#pragma unroll
  for (int tap = 0; tap < 9; ++tap) {
    float q = fminf(fmaxf(rintf(lw[t * 9 + tap] / s), -128.f), 127.f);
    wq[(size_t)o * 2304 + tap * 256 + t] = (signed char)q;
    ssum += (int)q;
  }
  if (which) {
    for (int off = 32; off; off >>= 1) ssum += __shfl_down(ssum, off, 64);
    __shared__ int si[4];
    if (!(t & 63)) si[t >> 6] = ssum;
    __syncthreads();
    if (t == 0) csumT[o] = 128 * (si[0] + si[1] + si[2] + si[3]);
  }
}

// ---------------- halo border fill (only borders; interior is fully overwritten) ----------------
__global__ __launch_bounds__(256) void border_kernel(signed char* __restrict__ halo, int v) {
  int n = blockIdx.x;
  int4 val = make_int4(v, v, v, v);
  for (int it = 0; it < 9; ++it) {
    int slot = it * 256 + threadIdx.x;
    if (slot >= 2112) break;                 // 132 border cells x 16 int4
    int cell = slot >> 4, sub = slot & 15;
    int h, w;
    if (cell < 34)      { h = 0;  w = cell; }
    else if (cell < 68) { h = 33; w = cell - 34; }
    else { int j = cell - 68; h = 1 + (j >> 1); w = (j & 1) * 33; }
    *(int4*)(halo + ((size_t)((n * 34 + h) * 34) + w) * 256 + sub * 16) = val;
  }
}

// ---------------- x quant + NCHW -> halo'd NHWC int8 ----------------
__global__ __launch_bounds__(256) void quantx_kernel(const float* __restrict__ x,
                                                     signed char* __restrict__ halo,
                                                     const unsigned* __restrict__ sc) {
  int n = blockIdx.x >> 5, h = blockIdx.x & 31;
  float s = u2f(sc[0]) / 127.f + 1e-12f;
  __shared__ float lds[32 * 257];
  const float* src = x + (size_t)n * 262144 + h * 32;
  int t = threadIdx.x;
  int wloc = t & 31, crow = t >> 5;
  for (int cc = 0; cc < 256; cc += 8) {
    int c = cc + crow;
    lds[wloc * 257 + c] = src[(size_t)c * 1024 + wloc];
  }
  __syncthreads();
  signed char* dst = halo + ((size_t)((n * 34 + h + 1) * 34) + 1) * 256;
  int c4 = (t & 63) * 4, wsub = t >> 6;
  for (int j = 0; j < 8; ++j) {
    int w_ = wsub * 8 + j;
    char4 q;
    q.x = (signed char)fminf(fmaxf(rintf(lds[w_ * 257 + c4 + 0] / s), -128.f), 127.f);
    q.y = (signed char)fminf(fmaxf(rintf(lds[w_ * 257 + c4 + 1] / s), -128.f), 127.f);
    q.z = (signed char)fminf(fmaxf(rintf(lds[w_ * 257 + c4 + 2] / s), -128.f), 127.f);
    q.w = (signed char)fminf(fmaxf(rintf(lds[w_ * 257 + c4 + 3] / s), -128.f), 127.f);
    *(char4*)(dst + (size_t)w_ * 256 + c4) = q;
  }
}

// ---------------- 256x256 int8 implicit-GEMM conv, m201-style sub-phase schedule ----------------
// K-chunk=64 (tap x 64ch), 36 chunks, 4 LDS regions, lookahead 3, counted vmcnt(8),
// per chunk: 2 sub-phases {ds_read 8|4, stage 2, barrier, lgkmcnt(0)+SB, setprio MFMA x16, barrier}.
// MODE 0: A=act pixels, B=weights, out[p*256+o], BN1 stats; MODE 1: A=weights, B=act, out[o*65536+p].
template <int MODE>
__global__ __launch_bounds__(512) void conv_i8_kernel(const signed char* __restrict__ aptr,
                                                      const signed char* __restrict__ bptr,
                                                      float* __restrict__ out,
                                                      const unsigned* __restrict__ sc,
                                                      float* __restrict__ part,
                                                      const int* __restrict__ csumT) {
  extern __shared__ char smem[];  // 147456: K-regions [0,128K), transpose [0,139264), stats [139264,147456)
  const int tid = threadIdx.x, lane = tid & 63, wid = tid >> 6;
  const int wm = wid >> 2, wn = wid & 3;     // 2M x 4N waves, per-wave 128x64
  int bid = blockIdx.x;
  bid = (bid & 7) * 32 + (bid >> 3);         // XCD-chunked swizzle (grid 256)
  const int pixBase = bid * 256;

  // staging: per-thread 2 x 16B slots per side; LDS layout
  // byte(row,k) = (row>>1)*128 + ((((row&1)<<2)|(k>>4)) ^ ((row>>1)&7))*16 + (k&15)
  long gA[2], gB[2];
  int ldst[2];
#pragma unroll
  for (int j = 0; j < 2; ++j) {
    int d = tid * 16 + j * 8192;
    int rp = d >> 7, s5 = (d >> 4) & 7, sp = s5 ^ (rp & 7);
    int row = rp * 2 + (sp >> 2), kc = (sp & 3) * 16;
    ldst[j] = d;
    int p = pixBase + row;
    int n = p >> 10, h = (p >> 5) & 31, w_ = p & 31;
    long ghalo = (long)((n * 34 + h) * 34 + w_) * 256 + kc;
    long gwt = (long)row * 2304 + kc;
    gA[j] = (MODE == 0) ? ghalo : gwt;
    gB[j] = (MODE == 0) ? gwt : ghalo;
  }

  const int g = lane >> 4, l15 = lane & 15;
  int aOff[8], bOff[4];
#pragma unroll
  for (int m = 0; m < 8; ++m) {
    int row = wm * 128 + m * 16 + l15; int rp = row >> 1;
    aOff[m] = rp * 128 + (((((row & 1) << 2) | g) ^ (rp & 7)) << 4);
  }
#pragma unroll
  for (int n = 0; n < 4; ++n) {
    int row = wn * 64 + n * 16 + l15; int rp = row >> 1;
    bOff[n] = rp * 128 + (((((row & 1) << 2) | g) ^ (rp & 7)) << 4);
  }

  const char* ac = (const char*)aptr;
  const char* bc = (const char*)bptr;
  char* lds = smem;

  auto stageH = [&](int P, int h) {
    int cblk = P / 9, tap = P - cblk * 9;    // c-outer, tap-inner (L2 reuse 1 chunk apart)
    int kh = tap / 3, kw = tap - kh * 3;
    long uH = (long)(kh * 34 + kw) * 256 + cblk * 64;
    long uW = (long)tap * 256 + cblk * 64;
    char* rb = lds + (P & 3) * 32768;
    if (h == 0) {
      long uA = (MODE == 0) ? uH : uW;
      async16(ac + gA[0] + uA, rb + ldst[0]);
      async16(ac + gA[1] + uA, rb + ldst[1]);
    } else {
      long uB = (MODE == 0) ? uW : uH;
      async16(bc + gB[0] + uB, rb + 16384 + ldst[0]);
      async16(bc + gB[1] + uB, rb + 16384 + ldst[1]);
    }
  };

  i32x4 acc[8][4];
#pragma unroll
  for (int m = 0; m < 8; ++m)
#pragma unroll
    for (int n = 0; n < 4; ++n)
#pragma unroll
      for (int r = 0; r < 4; ++r) acc[m][n][r] = 0;

  stageH(0, 0); stageH(0, 1); stageH(1, 0); stageH(1, 1); stageH(2, 0); stageH(2, 1);
  asm volatile("s_waitcnt vmcnt(8)" ::: "memory");
  __builtin_amdgcn_s_barrier();

  for (int P = 0; P < 36; ++P) {
    const char* rb = lds + (P & 3) * 32768;
    i32x4 a[8], b[4];
    // ---- sub-phase 0: frags {a0-3, b0-3}, stage A-half of chunk P+3 ----
#pragma unroll
    for (int m = 0; m < 4; ++m) a[m] = *(const i32x4*)(rb + aOff[m]);
#pragma unroll
    for (int n = 0; n < 4; ++n) b[n] = *(const i32x4*)(rb + 16384 + bOff[n]);
    if (P < 33) stageH(P + 3, 0);
    __builtin_amdgcn_s_barrier();
    asm volatile("s_waitcnt lgkmcnt(0)" ::: "memory");
    __builtin_amdgcn_sched_barrier(0);
    __builtin_amdgcn_s_setprio(1);
#pragma unroll
    for (int m = 0; m < 4; ++m)
#pragma unroll
      for (int n = 0; n < 4; ++n)
        acc[m][n] = __builtin_amdgcn_mfma_i32_16x16x64_i8(a[m], b[n], acc[m][n], 0, 0, 0);
    __builtin_amdgcn_s_setprio(0);
    __builtin_amdgcn_s_barrier();
    // ---- sub-phase 1: frags {a4-7}, stage B-half of chunk P+3 ----
#pragma unroll
    for (int m = 4; m < 8; ++m) a[m] = *(const i32x4*)(rb + aOff[m]);
    if (P < 33) stageH(P + 3, 1);
    __builtin_amdgcn_s_barrier();
    asm volatile("s_waitcnt lgkmcnt(0)" ::: "memory");
    __builtin_amdgcn_sched_barrier(0);
    __builtin_amdgcn_s_setprio(1);
#pragma unroll
    for (int m = 4; m < 8; ++m)
#pragma unroll
      for (int n = 0; n < 4; ++n)
        acc[m][n] = __builtin_amdgcn_mfma_i32_16x16x64_i8(a[m], b[n], acc[m][n], 0, 0, 0);
    __builtin_amdgcn_s_setprio(0);
    if (P < 33)       asm volatile("s_waitcnt vmcnt(8)" ::: "memory");
    else if (P == 33) asm volatile("s_waitcnt vmcnt(4)" ::: "memory");
    else if (P == 34) asm volatile("s_waitcnt vmcnt(0)" ::: "memory");
    if (P < 35) __builtin_amdgcn_s_barrier();
  }
  __syncthreads();

  float* twr = (float*)(smem + wid * 17408);   // per-wave 64x68 f32 transpose pad

  if constexpr (MODE == 0) {
    const float s = (u2f(sc[0]) / 127.f + 1e-12f) * (u2f(sc[1]) / 127.f + 1e-12f);
    float vs[4], vss[4], vmx[4], vmn[4];
#pragma unroll
    for (int n = 0; n < 4; ++n) { vs[n] = 0.f; vss[n] = 0.f; vmx[n] = -3.4e38f; vmn[n] = 3.4e38f; }
#pragma unroll
    for (int half = 0; half < 2; ++half) {
#pragma unroll
      for (int m2 = 0; m2 < 4; ++m2) {
        int m = half * 4 + m2;
#pragma unroll
        for (int n = 0; n < 4; ++n)
#pragma unroll
          for (int r = 0; r < 4; ++r) {
            float v = (float)acc[m][n][r] * s;
            vs[n] += v; vss[n] += v * v;
            vmx[n] = fmaxf(vmx[n], v); vmn[n] = fminf(vmn[n], v);
            twr[(m2 * 16 + g * 4 + r) * 68 + n * 16 + l15] = v;
          }
      }
#pragma unroll
      for (int it = 0; it < 16; ++it) {
        int i = it * 64 + lane;
        int row = i >> 4, c4 = (i & 15) << 2;
        float4 v4 = *(const float4*)(twr + row * 68 + c4);
        int p = pixBase + wm * 128 + half * 64 + row;
        *(float4*)(out + (size_t)p * 256 + wn * 64 + c4) = v4;
      }
    }
#pragma unroll
    for (int off = 16; off <= 32; off <<= 1)
#pragma unroll
      for (int n = 0; n < 4; ++n) {
        vs[n] += __shfl_xor(vs[n], off, 64);
        vss[n] += __shfl_xor(vss[n], off, 64);
        vmx[n] = fmaxf(vmx[n], __shfl_xor(vmx[n], off, 64));
        vmn[n] = fminf(vmn[n], __shfl_xor(vmn[n], off, 64));
      }
    __syncthreads();
    float* S0 = (float*)(smem + 139264);
    float* S1 = S0 + 512; float* S2 = S0 + 1024; float* S3 = S0 + 1536;
    if (lane < 16) {
#pragma unroll
      for (int n = 0; n < 4; ++n) {
        int ch = wn * 64 + n * 16 + l15;
        S0[wm * 256 + ch] = vs[n]; S1[wm * 256 + ch] = vss[n];
        S2[wm * 256 + ch] = vmx[n]; S3[wm * 256 + ch] = vmn[n];
      }
    }
    __syncthreads();
    if (tid < 256) {
      int idx = bid * 256 + tid;
      part[idx]          = S0[tid] + S0[256 + tid];
      part[65536 + idx]  = S1[tid] + S1[256 + tid];
      part[131072 + idx] = fmaxf(S2[tid], S2[256 + tid]);
      part[196608 + idx] = fminf(S3[tid], S3[256 + tid]);
    }
  } else {
    const float s = (u2f(sc[3]) / 255.f + 1e-12f) * (u2f(sc[2]) / 127.f + 1e-12f);
    float* SS = (float*)(smem + 139264);   // [4 wn][256 o]
    float* SQ = SS + 1024;
#pragma unroll
    for (int half = 0; half < 2; ++half) {
#pragma unroll
      for (int m2 = 0; m2 < 4; ++m2) {
        int m = half * 4 + m2;
        int o0 = wm * 128 + half * 64 + m2 * 16 + g * 4;
        i32x4 tc = *(const i32x4*)(csumT + o0);
        float sr[4] = {0.f, 0.f, 0.f, 0.f}, sq[4] = {0.f, 0.f, 0.f, 0.f};
#pragma unroll
        for (int n = 0; n < 4; ++n)
#pragma unroll
          for (int r = 0; r < 4; ++r) {
            float v = (float)(acc[m][n][r] + tc[r]) * s;
            sr[r] += v; sq[r] += v * v;
            twr[(m2 * 16 + g * 4 + r) * 68 + n * 16 + l15] = v;
          }
#pragma unroll
        for (int off = 1; off <= 8; off <<= 1)
#pragma unroll
          for (int r = 0; r < 4; ++r) {
            sr[r] += __shfl_xor(sr[r], off, 64);
            sq[r] += __shfl_xor(sq[r], off, 64);
          }
        if (l15 == 0) {
#pragma unroll
          for (int r = 0; r < 4; ++r) {
            SS[wn * 256 + o0 + r] = sr[r];
            SQ[wn * 256 + o0 + r] = sq[r];
          }
        }
      }
#pragma unroll
      for (int it = 0; it < 16; ++it) {
        int i = it * 64 + lane;
        int row = i >> 4, c4 = (i & 15) << 2;
        float4 v4 = *(const float4*)(twr + row * 68 + c4);
        int o = wm * 128 + half * 64 + row;
        *(float4*)(out + (size_t)o * 65536 + pixBase + wn * 64 + c4) = v4;
      }
    }
    __syncthreads();
    if (tid < 256) {
      float a = 0.f, b = 0.f;
#pragma unroll
      for (int w = 0; w < 4; ++w) { a += SS[w * 256 + tid]; b += SQ[w * 256 + tid]; }
      part[bid * 256 + tid] = a;
      part[65536 + bid * 256 + tid] = b;
    }
  }
}

// ---------------- BN1 finalize ----------------
__global__ __launch_bounds__(256) void bn1fin_kernel(const float* __restrict__ part,
                                                     const float* __restrict__ g,
                                                     const float* __restrict__ be,
                                                     float* __restrict__ bnA, float* __restrict__ bnB,
                                                     unsigned* __restrict__ sc) {
  int o0 = blockIdx.x * 32;
  int t = threadIdx.x, oc = t & 31, mq = t >> 5;
  float s = 0.f, ss = 0.f, mx = -3.4e38f, mn = 3.4e38f;
  for (int j = 0; j < 32; ++j) {
    int i = (mq * 32 + j) * 256 + o0 + oc;
    s += part[i]; ss += part[65536 + i];
    mx = fmaxf(mx, part[131072 + i]); mn = fminf(mn, part[196608 + i]);
  }
  __shared__ float red[4][8][32];
  red[0][mq][oc] = s; red[1][mq][oc] = ss; red[2][mq][oc] = mx; red[3][mq][oc] = mn;
  __syncthreads();
  if (t < 32) {
    s = 0.f; ss = 0.f; mx = -3.4e38f; mn = 3.4e38f;
    for (int q = 0; q < 8; ++q) {
      s += red[0][q][t]; ss += red[1][q][t];
      mx = fmaxf(mx, red[2][q][t]); mn = fminf(mn, red[3][q][t]);
    }
    float mean = s * (1.f / 65536.f);
    float var = fmaxf(ss * (1.f / 65536.f) - mean * mean, 0.f);
    int o = o0 + t;
    float a = g[o] * rsqrtf(var + 1e-5f);
    float b2 = be[o] - mean * a;
    bnA[o] = a; bnB[o] = b2;
    float m = fmaxf(fmaxf(a * mx + b2, a * mn + b2), 0.f);
    atomicMax(sc + 3, __float_as_uint(m));
  }
}

// ---------------- BN2 finalize ----------------
__global__ __launch_bounds__(256) void bn2fin_kernel(const float* __restrict__ part,
                                                     const float* __restrict__ g,
                                                     const float* __restrict__ be,
                                                     float* __restrict__ bnA2, float* __restrict__ bnB2) {
  int o0 = blockIdx.x * 32;
  int t = threadIdx.x, oc = t & 31, mq = t >> 5;
  float s = 0.f, ss = 0.f;
  for (int j = 0; j < 32; ++j) {
    int i = (mq * 32 + j) * 256 + o0 + oc;
    s += part[i]; ss += part[65536 + i];
  }
  __shared__ float red[2][8][32];
  red[0][mq][oc] = s; red[1][mq][oc] = ss;
  __syncthreads();
  if (t < 32) {
    s = 0.f; ss = 0.f;
    for (int q = 0; q < 8; ++q) { s += red[0][q][t]; ss += red[1][q][t]; }
    float mean = s * (1.f / 65536.f);
    float var = fmaxf(ss * (1.f / 65536.f) - mean * mean, 0.f);
    int o = o0 + t;
    float a = g[o] * rsqrtf(var + 1e-5f);
    bnA2[o] = a;
    bnB2[o] = be[o] - mean * a;
  }
}

// ---------------- BN1 apply + ReLU + unsigned quant -> int8 halo (u-128, pad=-128) ----------------
__global__ __launch_bounds__(256) void apply_kernel(const float* __restrict__ y,
                                                    const float* __restrict__ bnA,
                                                    const float* __restrict__ bnB,
                                                    const unsigned* __restrict__ sc,
                                                    signed char* __restrict__ halo) {
  int t = threadIdx.x;
  int c4 = (t & 63) * 4;
  int psub = t >> 6;
  float s2 = u2f(sc[3]) / 255.f + 1e-12f;
  float4 a = *(const float4*)(bnA + c4);
  float4 b = *(const float4*)(bnB + c4);
  int p0 = blockIdx.x * 16 + psub;
  for (int j = 0; j < 4; ++j) {
    int p = p0 + j * 4;
    float4 v = *(const float4*)(y + (size_t)p * 256 + c4);
    char4 q;
    q.x = (signed char)((int)fminf(fmaxf(rintf(fmaxf(a.x * v.x + b.x, 0.f) / s2), 0.f), 255.f) - 128);
    q.y = (signed char)((int)fminf(fmaxf(rintf(fmaxf(a.y * v.y + b.y, 0.f) / s2), 0.f), 255.f) - 128);
    q.z = (signed char)((int)fminf(fmaxf(rintf(fmaxf(a.z * v.z + b.z, 0.f) / s2), 0.f), 255.f) - 128);
    q.w = (signed char)((int)fminf(fmaxf(rintf(fmaxf(a.w * v.w + b.w, 0.f) / s2), 0.f), 255.f) - 128);
    int n = p >> 10, h = (p >> 5) & 31, w_ = p & 31;
    *(char4*)(halo + ((size_t)((n * 34 + h + 1) * 34) + (w_ + 1)) * 256 + c4) = q;
  }
}

// ---------------- BN2 + residual + ReLU -> NCHW out ----------------
__global__ __launch_bounds__(256) void final_kernel(const float* __restrict__ y2,
                                                    const float* __restrict__ x,
                                                    const float* __restrict__ bnA2,
                                                    const float* __restrict__ bnB2,
                                                    float* __restrict__ out) {
  int tid = blockIdx.x * 256 + threadIdx.x;
  for (int i = tid; i < 4194304; i += 1048576) {
    int e = i << 2;
    int o = (e >> 10) & 255;
    int n = e >> 18, hw = e & 1023;
    float4 v = *(const float4*)(y2 + (((size_t)o << 16) + (n << 10) + hw));
    float4 xr = ((const float4*)x)[i];
    float a = bnA2[o], b = bnB2[o];
    float4 r;
    r.x = fmaxf(a * v.x + b + xr.x, 0.f);
    r.y = fmaxf(a * v.y + b + xr.y, 0.f);
    r.z = fmaxf(a * v.z + b + xr.z, 0.f);
    r.w = fmaxf(a * v.w + b + xr.w, 0.f);
    ((float4*)out)[i] = r;
  }
}

extern "C" void kernel_launch(void* const* d_in, const int* in_sizes, int n_in,
                              void* d_out, int out_size, void* d_ws, size_t ws_size,
                              hipStream_t stream) {
  const float* x  = (const float*)d_in[0];
  const float* w1 = (const float*)d_in[1];
  const float* g1 = (const float*)d_in[2];
  const float* b1 = (const float*)d_in[3];
  const float* w2 = (const float*)d_in[4];
  const float* g2 = (const float*)d_in[5];
  const float* b2 = (const float*)d_in[6];
  float* out = (float*)d_out;
  char* ws = (char*)d_ws;

  // workspace (~88.3 MB)
  unsigned* sc = (unsigned*)ws;                      // sc[0..2]=absmax, sc[3]=relu-max
  float* bnA   = (float*)(ws + 4096);
  float* bnB   = (float*)(ws + 8192);
  float* bnA2  = (float*)(ws + 12288);
  float* bnB2  = (float*)(ws + 16384);
  int*   csumT = (int*)(ws + 20480);                 // 1 KB
  float* part  = (float*)(ws + 24576);               // 1 MB (4 slabs x 256KB)
  signed char* wq1  = (signed char*)(ws + 24576 + 1048576);
  signed char* wq2  = wq1 + 589824;
  signed char* halo = wq2 + 589824;                  // 18,939,904 B (reused for conv2 input)
  float* convb = (float*)(ws + 24576 + 1048576 + 2 * 589824 + 18939904);  // 64 MB

  hipFuncSetAttribute((const void*)(conv_i8_kernel<0>), hipFuncAttributeMaxDynamicSharedMemorySize, 147456);
  hipFuncSetAttribute((const void*)(conv_i8_kernel<1>), hipFuncAttributeMaxDynamicSharedMemorySize, 147456);

  hipMemsetAsync(sc, 0, 64, stream);
  border_kernel<<<64, 256, 0, stream>>>(halo, 0);                  // pad=0 for signed conv1

  absmax3_kernel<<<1920, 256, 0, stream>>>(x, w1, w2, sc);
  quantw_kernel<<<512, 256, 0, stream>>>(w1, w2, wq1, wq2, sc, csumT);
  quantx_kernel<<<2048, 256, 0, stream>>>(x, halo, sc);
  conv_i8_kernel<0><<<256, 512, 147456, stream>>>(halo, wq1, convb, sc, part, csumT);
  bn1fin_kernel<<<8, 256, 0, stream>>>(part, g1, b1, bnA, bnB, sc);
  border_kernel<<<64, 256, 0, stream>>>(halo, (int)0x80808080u);   // pad=-128 for offset conv2
  apply_kernel<<<4096, 256, 0, stream>>>(convb, bnA, bnB, sc, halo);
  conv_i8_kernel<1><<<256, 512, 147456, stream>>>(wq2, halo, convb, sc, part, csumT);
  bn2fin_kernel<<<8, 256, 0, stream>>>(part, g2, b2, bnA2, bnB2);
  final_kernel<<<4096, 256, 0, stream>>>(convb, x, bnA2, bnB2, out);
}

// Round 7
// 301.113 us; speedup vs baseline: 1.6759x; 1.0487x over previous
//
#include <hip/hip_runtime.h>

typedef __attribute__((ext_vector_type(4))) int i32x4;

typedef __attribute__((address_space(1))) unsigned int uglobal;
typedef __attribute__((address_space(3))) unsigned int ulocal;

__device__ __forceinline__ void async16(const void* g, void* l) {
  __builtin_amdgcn_global_load_lds((const uglobal*)g, (ulocal*)l, 16, 0, 0);
}
__device__ __forceinline__ float u2f(unsigned u) { return __uint_as_float(u); }

// order-preserving float<->uint key (works for negatives) for atomicMax/Min
__device__ __forceinline__ unsigned fkey(float f) {
  unsigned u = __float_as_uint(f);
  return u ^ (unsigned)(((int)u >> 31) | (int)0x80000000);
}
__device__ __forceinline__ float funkey(unsigned k) {
  unsigned u = (k & 0x80000000u) ? (k ^ 0x80000000u) : ~k;
  return __uint_as_float(u);
}

// grid barrier: 256 blocks, all co-resident (1 block/CU, grid == CU count)
__device__ __forceinline__ void gridbar(unsigned* ctr) {
  __syncthreads();
  if (threadIdx.x == 0) {
    __threadfence();
    atomicAdd(ctr, 1u);
    while (atomicAdd(ctr, 0u) < 256u) __builtin_amdgcn_s_sleep(2);
    __threadfence();
  }
  __syncthreads();
}

// ---------------- fused absmax over x, w1, w2 ----------------
__global__ __launch_bounds__(256) void absmax3_kernel(const float* __restrict__ x,
                                                      const float* __restrict__ w1,
                                                      const float* __restrict__ w2,
                                                      unsigned* __restrict__ sc) {
  int b = blockIdx.x;
  const float* src; int n4, b0, nb, seg;
  if (b < 1792)      { src = x;  n4 = 4194304; b0 = 0;    nb = 1792; seg = 0; }
  else if (b < 1856) { src = w1; n4 = 147456;  b0 = 1792; nb = 64;   seg = 1; }
  else               { src = w2; n4 = 147456;  b0 = 1856; nb = 64;   seg = 2; }
  float m = 0.f;
  int stride = nb * 256;
  for (int i = (b - b0) * 256 + threadIdx.x; i < n4; i += stride) {
    float4 v = ((const float4*)src)[i];
    m = fmaxf(fmaxf(fabsf(v.x), fabsf(v.y)), fmaxf(fmaxf(fabsf(v.z), fabsf(v.w)), m));
  }
  for (int off = 32; off; off >>= 1) m = fmaxf(m, __shfl_down(m, off, 64));
  __shared__ float sm[4];
  int lane = threadIdx.x & 63, wv = threadIdx.x >> 6;
  if (!lane) sm[wv] = m;
  __syncthreads();
  if (threadIdx.x == 0)
    atomicMax(sc + seg, __float_as_uint(fmaxf(fmaxf(sm[0], sm[1]), fmaxf(sm[2], sm[3]))));
}

// ---------------- weight quant + relayout + fused tapsum ----------------
__global__ __launch_bounds__(256) void quantw_kernel(const float* __restrict__ w1,
                                                     const float* __restrict__ w2,
                                                     signed char* __restrict__ wq1,
                                                     signed char* __restrict__ wq2,
                                                     const unsigned* __restrict__ sc,
                                                     int* __restrict__ csumT) {
  int b = blockIdx.x, which = b >> 8, o = b & 255, t = threadIdx.x;
  const float* w = which ? w2 : w1;
  signed char* wq = which ? wq2 : wq1;
  float s = u2f(sc[1 + which]) / 127.f + 1e-12f;
  __shared__ float lw[2304];
  for (int j = t; j < 2304; j += 256) lw[j] = w[(size_t)o * 2304 + j];
  __syncthreads();
  int ssum = 0;
#pragma unroll
  for (int tap = 0; tap < 9; ++tap) {
    float q = fminf(fmaxf(rintf(lw[t * 9 + tap] / s), -128.f), 127.f);
    wq[(size_t)o * 2304 + tap * 256 + t] = (signed char)q;
    ssum += (int)q;
  }
  if (which) {
    for (int off = 32; off; off >>= 1) ssum += __shfl_down(ssum, off, 64);
    __shared__ int si[4];
    if (!(t & 63)) si[t >> 6] = ssum;
    __syncthreads();
    if (t == 0) csumT[o] = 128 * (si[0] + si[1] + si[2] + si[3]);
  }
}

// ---------------- halo border fill for BOTH halos (borders only) ----------------
__global__ __launch_bounds__(256) void border_kernel(signed char* __restrict__ h1,
                                                     signed char* __restrict__ h2) {
  int which = blockIdx.x >> 6, n = blockIdx.x & 63;
  signed char* halo = which ? h2 : h1;
  int v = which ? (int)0x80808080u : 0;
  int4 val = make_int4(v, v, v, v);
  for (int it = 0; it < 9; ++it) {
    int slot = it * 256 + threadIdx.x;
    if (slot >= 2112) break;                 // 132 border cells x 16 int4
    int cell = slot >> 4, sub = slot & 15;
    int h, w;
    if (cell < 34)      { h = 0;  w = cell; }
    else if (cell < 68) { h = 33; w = cell - 34; }
    else { int j = cell - 68; h = 1 + (j >> 1); w = (j & 1) * 33; }
    *(int4*)(halo + ((size_t)((n * 34 + h) * 34) + w) * 256 + sub * 16) = val;
  }
}

// ---------------- x quant + NCHW -> halo'd NHWC int8 ----------------
__global__ __launch_bounds__(256) void quantx_kernel(const float* __restrict__ x,
                                                     signed char* __restrict__ halo,
                                                     const unsigned* __restrict__ sc) {
  int n = blockIdx.x >> 5, h = blockIdx.x & 31;
  float s = u2f(sc[0]) / 127.f + 1e-12f;
  __shared__ float lds[32 * 257];
  const float* src = x + (size_t)n * 262144 + h * 32;
  int t = threadIdx.x;
  int wloc = t & 31, crow = t >> 5;
  for (int cc = 0; cc < 256; cc += 8) {
    int c = cc + crow;
    lds[wloc * 257 + c] = src[(size_t)c * 1024 + wloc];
  }
  __syncthreads();
  signed char* dst = halo + ((size_t)((n * 34 + h + 1) * 34) + 1) * 256;
  int c4 = (t & 63) * 4, wsub = t >> 6;
  for (int j = 0; j < 8; ++j) {
    int w_ = wsub * 8 + j;
    char4 q;
    q.x = (signed char)fminf(fmaxf(rintf(lds[w_ * 257 + c4 + 0] / s), -128.f), 127.f);
    q.y = (signed char)fminf(fmaxf(rintf(lds[w_ * 257 + c4 + 1] / s), -128.f), 127.f);
    q.z = (signed char)fminf(fmaxf(rintf(lds[w_ * 257 + c4 + 2] / s), -128.f), 127.f);
    q.w = (signed char)fminf(fmaxf(rintf(lds[w_ * 257 + c4 + 3] / s), -128.f), 127.f);
    *(char4*)(dst + (size_t)w_ * 256 + c4) = q;
  }
}

// ---------------- mega conv kernels: 256x256 int8 implicit-GEMM (round-4 schedule)
// + fused BN via grid barrier, acc kept in registers across the barrier.
// MODE 0: conv1 -> stats -> bar -> BN1+ReLU+uquant -> int8 halo2
// MODE 1: conv2 -> stats -> bar -> BN2+residual+ReLU -> fp32 NCHW out
template <int MODE>
__global__ __launch_bounds__(512) void conv_i8_kernel(const signed char* __restrict__ aptr,
                                                      const signed char* __restrict__ bptr,
                                                      const float* __restrict__ xres,
                                                      float* __restrict__ outp,
                                                      signed char* __restrict__ halo2,
                                                      const float* __restrict__ gam,
                                                      const float* __restrict__ bet,
                                                      unsigned* __restrict__ sc,
                                                      float* __restrict__ red,
                                                      const int* __restrict__ csumT) {
  extern __shared__ char smem[];  // 147456
  const int tid = threadIdx.x, lane = tid & 63, wid = tid >> 6;
  const int wm = wid >> 2, wn = wid & 3;     // 2M x 4N waves, per-wave 128x64
  int bid = blockIdx.x;
  bid = (bid & 7) * 32 + (bid >> 3);         // XCD-chunked swizzle (grid 256)
  const int pixBase = bid * 256;

  long gA[2], gB[2];
  int ldst[2];
#pragma unroll
  for (int j = 0; j < 2; ++j) {
    int d = tid * 16 + j * 8192;
    int rp = d >> 7, s5 = (d >> 4) & 7, sp = s5 ^ (rp & 7);
    int row = rp * 2 + (sp >> 2), kc = (sp & 3) * 16;
    ldst[j] = d;
    int p = pixBase + row;
    int n = p >> 10, h = (p >> 5) & 31, w_ = p & 31;
    long ghalo = (long)((n * 34 + h) * 34 + w_) * 256 + kc;
    long gwt = (long)row * 2304 + kc;
    gA[j] = (MODE == 0) ? ghalo : gwt;
    gB[j] = (MODE == 0) ? gwt : ghalo;
  }

  const int g = lane >> 4, l15 = lane & 15;
  int aOff[8], bOff[4];
#pragma unroll
  for (int m = 0; m < 8; ++m) {
    int row = wm * 128 + m * 16 + l15; int rp = row >> 1;
    aOff[m] = rp * 128 + (((((row & 1) << 2) | g) ^ (rp & 7)) << 4);
  }
#pragma unroll
  for (int n = 0; n < 4; ++n) {
    int row = wn * 64 + n * 16 + l15; int rp = row >> 1;
    bOff[n] = rp * 128 + (((((row & 1) << 2) | g) ^ (rp & 7)) << 4);
  }

  const char* ac = (const char*)aptr;
  const char* bc = (const char*)bptr;
  char* lds = smem;

  auto stage = [&](int P) {
    int cblk = P / 9, tap = P - cblk * 9;    // c-outer, tap-inner
    int kh = tap / 3, kw = tap - kh * 3;
    long uH = (long)(kh * 34 + kw) * 256 + cblk * 64;
    long uW = (long)tap * 256 + cblk * 64;
    long uA = (MODE == 0) ? uH : uW;
    long uB = (MODE == 0) ? uW : uH;
    char* rb = lds + (P & 3) * 32768;
    async16(ac + gA[0] + uA, rb + ldst[0]);
    async16(ac + gA[1] + uA, rb + ldst[1]);
    async16(bc + gB[0] + uB, rb + 16384 + ldst[0]);
    async16(bc + gB[1] + uB, rb + 16384 + ldst[1]);
  };

  i32x4 acc[8][4];
#pragma unroll
  for (int m = 0; m < 8; ++m)
#pragma unroll
    for (int n = 0; n < 4; ++n)
#pragma unroll
      for (int r = 0; r < 4; ++r) acc[m][n][r] = 0;

  stage(0); stage(1); stage(2);
  asm volatile("s_waitcnt vmcnt(8)" ::: "memory");
  asm volatile("s_barrier" ::: "memory");

  for (int P = 0; P < 36; ++P) {
    if (P < 33) stage(P + 3);
    const char* rb = lds + (P & 3) * 32768;
    i32x4 a[8], b[4];
#pragma unroll
    for (int m = 0; m < 8; ++m) a[m] = *(const i32x4*)(rb + aOff[m]);
#pragma unroll
    for (int n = 0; n < 4; ++n) b[n] = *(const i32x4*)(rb + 16384 + bOff[n]);
    __builtin_amdgcn_s_setprio(1);
#pragma unroll
    for (int m = 0; m < 8; ++m)
#pragma unroll
      for (int n = 0; n < 4; ++n)
        acc[m][n] = __builtin_amdgcn_mfma_i32_16x16x64_i8(a[m], b[n], acc[m][n], 0, 0, 0);
    __builtin_amdgcn_s_setprio(0);
    if (P < 33)       asm volatile("s_waitcnt vmcnt(8)" ::: "memory");
    else if (P == 33) asm volatile("s_waitcnt vmcnt(4)" ::: "memory");
    else if (P == 34) asm volatile("s_waitcnt vmcnt(0)" ::: "memory");
    if (P < 35) asm volatile("s_barrier" ::: "memory");
  }
  __syncthreads();

  unsigned* redu = (unsigned*)red;
  float* twr = (float*)(smem + wid * 17408);   // per-wave 64x68 f32 transpose pad

  if constexpr (MODE == 0) {
    // ---- raw per-channel partial stats (undequantized) ----
    float vs[4], vss[4], vmx[4], vmn[4];
#pragma unroll
    for (int n = 0; n < 4; ++n) { vs[n] = 0.f; vss[n] = 0.f; vmx[n] = -3.4e38f; vmn[n] = 3.4e38f; }
#pragma unroll
    for (int m = 0; m < 8; ++m)
#pragma unroll
      for (int n = 0; n < 4; ++n)
#pragma unroll
        for (int r = 0; r < 4; ++r) {
          float v = (float)acc[m][n][r];
          vs[n] += v; vss[n] += v * v;
          vmx[n] = fmaxf(vmx[n], v); vmn[n] = fminf(vmn[n], v);
        }
#pragma unroll
    for (int off = 16; off <= 32; off <<= 1)
#pragma unroll
      for (int n = 0; n < 4; ++n) {
        vs[n] += __shfl_xor(vs[n], off, 64);
        vss[n] += __shfl_xor(vss[n], off, 64);
        vmx[n] = fmaxf(vmx[n], __shfl_xor(vmx[n], off, 64));
        vmn[n] = fminf(vmn[n], __shfl_xor(vmn[n], off, 64));
      }
    float* S0 = (float*)(smem + 139264);
    float* S1 = S0 + 512; float* S2 = S0 + 1024; float* S3 = S0 + 1536;
    if (lane < 16) {
#pragma unroll
      for (int n = 0; n < 4; ++n) {
        int ch = wn * 64 + n * 16 + l15;
        S0[wm * 256 + ch] = vs[n]; S1[wm * 256 + ch] = vss[n];
        S2[wm * 256 + ch] = vmx[n]; S3[wm * 256 + ch] = vmn[n];
      }
    }
    __syncthreads();
    if (tid < 256) {
      atomicAdd(red + tid, S0[tid] + S0[256 + tid]);
      atomicAdd(red + 256 + tid, S1[tid] + S1[256 + tid]);
      atomicMax(redu + 512 + tid, fkey(fmaxf(S2[tid], S2[256 + tid])));
      atomicMin(redu + 768 + tid, fkey(fminf(S3[tid], S3[256 + tid])));
    }
    gridbar(sc + 8);
    // ---- redundant per-block BN1 finalize (bit-identical across blocks) ----
    float* bnAl = (float*)(smem + 139264);
    float* bnBl = bnAl + 256;
    float* rmx  = bnAl + 512;
    const float sDq = (u2f(sc[0]) / 127.f + 1e-12f) * (u2f(sc[1]) / 127.f + 1e-12f);
    if (tid < 256) {
      float su  = atomicAdd(red + tid, 0.f);          // atomic reads: coherent across XCDs
      float sq  = atomicAdd(red + 256 + tid, 0.f);
      float mxr = funkey(atomicAdd(redu + 512 + tid, 0u));
      float mnr = funkey(atomicAdd(redu + 768 + tid, 0u));
      float mean = sDq * su * (1.f / 65536.f);
      float e2 = sDq * sDq * sq * (1.f / 65536.f);
      float var = fmaxf(e2 - mean * mean, 0.f);
      float a = gam[tid] * rsqrtf(var + 1e-5f);
      float b = bet[tid] - mean * a;
      float aS = a * sDq;
      bnAl[tid] = aS; bnBl[tid] = b;
      rmx[tid] = fmaxf(fmaxf(aS * mxr + b, aS * mnr + b), 0.f);
    }
    __syncthreads();
    for (int st = 128; st; st >>= 1) {
      if (tid < st) rmx[tid] = fmaxf(rmx[tid], rmx[tid + st]);
      __syncthreads();
    }
    float s2 = rmx[0] * (1.f / 255.f) + 1e-12f;
    if (tid == 0) ((float*)sc)[3] = s2;               // for megaB (cross-kernel)
    float is2 = 1.f / s2;
    float aCh[4], bCh[4];
#pragma unroll
    for (int n = 0; n < 4; ++n) {
      aCh[n] = bnAl[wn * 64 + n * 16 + l15];
      bCh[n] = bnBl[wn * 64 + n * 16 + l15];
    }
    // ---- apply BN1+ReLU, transpose in LDS, quantize, write int8 halo2 ----
#pragma unroll
    for (int half = 0; half < 2; ++half) {
#pragma unroll
      for (int m2 = 0; m2 < 4; ++m2) {
        int m = half * 4 + m2;
#pragma unroll
        for (int n = 0; n < 4; ++n)
#pragma unroll
          for (int r = 0; r < 4; ++r) {
            float y = fmaxf(aCh[n] * (float)acc[m][n][r] + bCh[n], 0.f);
            twr[(m2 * 16 + g * 4 + r) * 68 + n * 16 + l15] = y;
          }
      }
#pragma unroll
      for (int it = 0; it < 16; ++it) {
        int i = it * 64 + lane;
        int row = i >> 4, c4 = (i & 15) << 2;
        float4 y4 = *(const float4*)(twr + row * 68 + c4);
        char4 q;
        q.x = (signed char)((int)fminf(fmaxf(rintf(y4.x * is2), 0.f), 255.f) - 128);
        q.y = (signed char)((int)fminf(fmaxf(rintf(y4.y * is2), 0.f), 255.f) - 128);
        q.z = (signed char)((int)fminf(fmaxf(rintf(y4.z * is2), 0.f), 255.f) - 128);
        q.w = (signed char)((int)fminf(fmaxf(rintf(y4.w * is2), 0.f), 255.f) - 128);
        int p = pixBase + wm * 128 + half * 64 + row;
        int n_ = p >> 10, h = (p >> 5) & 31, w_ = p & 31;
        *(char4*)(halo2 + ((size_t)((n_ * 34 + h + 1) * 34) + (w_ + 1)) * 256 + wn * 64 + c4) = q;
      }
    }
  } else {
    // ---- raw per-o partial stats (with +128*sum(w) correction) ----
    const float s2f = ((const float*)sc)[3];
    const float sDq = s2f * (u2f(sc[2]) / 127.f + 1e-12f);
    float* SS = (float*)(smem + 139264);   // [4 wn][256 o]
    float* SQ = SS + 1024;
#pragma unroll
    for (int half = 0; half < 2; ++half)
#pragma unroll
      for (int m2 = 0; m2 < 4; ++m2) {
        int m = half * 4 + m2;
        int o0 = wm * 128 + half * 64 + m2 * 16 + g * 4;
        i32x4 tc = *(const i32x4*)(csumT + o0);
        float sr[4] = {0.f, 0.f, 0.f, 0.f}, sq_[4] = {0.f, 0.f, 0.f, 0.f};
#pragma unroll
        for (int n = 0; n < 4; ++n)
#pragma unroll
          for (int r = 0; r < 4; ++r) {
            float vd = (float)(acc[m][n][r] + tc[r]);
            sr[r] += vd; sq_[r] += vd * vd;
          }
#pragma unroll
        for (int off = 1; off <= 8; off <<= 1)
#pragma unroll
          for (int r = 0; r < 4; ++r) {
            sr[r] += __shfl_xor(sr[r], off, 64);
            sq_[r] += __shfl_xor(sq_[r], off, 64);
          }
        if (l15 == 0) {
#pragma unroll
          for (int r = 0; r < 4; ++r) {
            SS[wn * 256 + o0 + r] = sr[r];
            SQ[wn * 256 + o0 + r] = sq_[r];
          }
        }
      }
    __syncthreads();
    if (tid < 256) {
      float a_ = 0.f, b_ = 0.f;
#pragma unroll
      for (int w = 0; w < 4; ++w) { a_ += SS[w * 256 + tid]; b_ += SQ[w * 256 + tid]; }
      atomicAdd(red + 1024 + tid, a_);
      atomicAdd(red + 1280 + tid, b_);
    }
    gridbar(sc + 9);
    // ---- redundant BN2 finalize ----
    float* a2l = (float*)(smem + 139264);
    float* b2l = a2l + 256;
    if (tid < 256) {
      float su = atomicAdd(red + 1024 + tid, 0.f);
      float sq = atomicAdd(red + 1280 + tid, 0.f);
      float mean = sDq * su * (1.f / 65536.f);
      float e2 = sDq * sDq * sq * (1.f / 65536.f);
      float var = fmaxf(e2 - mean * mean, 0.f);
      float a = gam[tid] * rsqrtf(var + 1e-5f);
      b2l[tid] = bet[tid] - mean * a;
      a2l[tid] = a * sDq;
    }
    __syncthreads();
    // ---- BN2 + residual + ReLU -> NCHW out (transposed via LDS, float4 both sides) ----
#pragma unroll
    for (int half = 0; half < 2; ++half) {
#pragma unroll
      for (int m2 = 0; m2 < 4; ++m2) {
        int m = half * 4 + m2;
        int o0 = wm * 128 + half * 64 + m2 * 16 + g * 4;
        i32x4 tc = *(const i32x4*)(csumT + o0);
#pragma unroll
        for (int n = 0; n < 4; ++n)
#pragma unroll
          for (int r = 0; r < 4; ++r)
            twr[(m2 * 16 + g * 4 + r) * 68 + n * 16 + l15] = (float)(acc[m][n][r] + tc[r]);
      }
#pragma unroll
      for (int it = 0; it < 16; ++it) {
        int i = it * 64 + lane;
        int row = i >> 4, c4 = (i & 15) << 2;
        int o = wm * 128 + half * 64 + row;
        float4 v4 = *(const float4*)(twr + row * 68 + c4);
        int p = pixBase + wn * 64 + c4;
        int n_ = p >> 10, hw = p & 1023;
        size_t base = ((size_t)n_ << 18) + ((size_t)o << 10) + hw;
        float4 x4 = *(const float4*)(xres + base);
        float a = a2l[o], b = b2l[o];
        float4 r4;
        r4.x = fmaxf(a * v4.x + b + x4.x, 0.f);
        r4.y = fmaxf(a * v4.y + b + x4.y, 0.f);
        r4.z = fmaxf(a * v4.z + b + x4.z, 0.f);
        r4.w = fmaxf(a * v4.w + b + x4.w, 0.f);
        *(float4*)(outp + base) = r4;
      }
    }
  }
}

extern "C" void kernel_launch(void* const* d_in, const int* in_sizes, int n_in,
                              void* d_out, int out_size, void* d_ws, size_t ws_size,
                              hipStream_t stream) {
  const float* x  = (const float*)d_in[0];
  const float* w1 = (const float*)d_in[1];
  const float* g1 = (const float*)d_in[2];
  const float* b1 = (const float*)d_in[3];
  const float* w2 = (const float*)d_in[4];
  const float* g2 = (const float*)d_in[5];
  const float* b2 = (const float*)d_in[6];
  float* out = (float*)d_out;
  char* ws = (char*)d_ws;

  // workspace (~39 MB)
  unsigned* sc = (unsigned*)ws;               // [0..2] absmax, [3] s2(float), [8]/[9] barrier ctrs
  float* red   = (float*)(ws + 1024);         // sum1|ssq1|maxk|mink|sum2|ssq2 (6 x 256)
  int* csumT   = (int*)(ws + 7168);           // 1 KB
  signed char* wq1   = (signed char*)(ws + 8192);
  signed char* wq2   = wq1 + 589824;
  signed char* halo1 = wq2 + 589824;          // 18,939,904 B
  signed char* halo2 = halo1 + 18939904;      // 18,939,904 B

  hipFuncSetAttribute((const void*)(conv_i8_kernel<0>), hipFuncAttributeMaxDynamicSharedMemorySize, 147456);
  hipFuncSetAttribute((const void*)(conv_i8_kernel<1>), hipFuncAttributeMaxDynamicSharedMemorySize, 147456);

  hipMemsetAsync(ws, 0, 4096, stream);                 // sc + sum1 + ssq1 + maxk(0 = -inf key)
  hipMemsetAsync(ws + 4096, 0xFF, 1024, stream);       // mink = +inf key
  hipMemsetAsync(ws + 5120, 0, 2048, stream);          // sum2 + ssq2

  border_kernel<<<128, 256, 0, stream>>>(halo1, halo2);           // h1 pad=0, h2 pad=-128
  absmax3_kernel<<<1920, 256, 0, stream>>>(x, w1, w2, sc);
  quantw_kernel<<<512, 256, 0, stream>>>(w1, w2, wq1, wq2, sc, csumT);
  quantx_kernel<<<2048, 256, 0, stream>>>(x, halo1, sc);
  conv_i8_kernel<0><<<256, 512, 147456, stream>>>(halo1, wq1, nullptr, nullptr, halo2,
                                                  g1, b1, sc, red, csumT);
  conv_i8_kernel<1><<<256, 512, 147456, stream>>>(wq2, halo2, x, out, nullptr,
                                                  g2, b2, sc, red, csumT);
}